// Round 10
// baseline (563.744 us; speedup 1.0000x reference)
//
#include <hip/hip_runtime.h>
#include <hip/hip_bf16.h>
#include <math.h>

#define B_   64
#define N_   2048
#define E_   32768
#define K_   1024
#define F_   128
#define C_   384
#define NB_  (B_ * N_)

typedef __bf16 bf16x8 __attribute__((ext_vector_type(8)));
typedef float  f32x4  __attribute__((ext_vector_type(4)));

__device__ __forceinline__ float bf2f(unsigned int u) {
  return __uint_as_float(u << 16);   // uses low 16 bits
}
__device__ __forceinline__ unsigned int f2bf(float f) {
  unsigned int x = __float_as_uint(f);
  return (x + 0x7fffu + ((x >> 16) & 1u)) >> 16;   // RNE
}

// ---------------- graph prep: 4 blocks per graph, each owns a 512-node range ----------------
__global__ __launch_bounds__(1024) void k_prep(const int* __restrict__ src,
                                               const int* __restrict__ dst,
                                               float* __restrict__ norm_s,
                                               float* __restrict__ norm_d,
                                               int* __restrict__ row_ptr,
                                               int* __restrict__ csr) {
  __shared__ int h_in[512];      // deg_in for my range, later reused as fill counters
  __shared__ int h_out[512];     // deg_out for my range
  __shared__ int rowst[512];     // row starts (global) for my range
  __shared__ int part[512];      // scan workspace
  __shared__ int rtot[4];        // edges per dst-range (whole graph)
  int b = blockIdx.x >> 2, r = blockIdx.x & 3;
  int lo = r << 9;
  int t = threadIdx.x;
  if (t < 512) { h_in[t] = 0; h_out[t] = 0; }
  if (t < 4) rtot[t] = 0;
  __syncthreads();
  const int* sp = src + (size_t)b * E_;
  const int* dp = dst + (size_t)b * E_;
  int c0 = 0, c1 = 0, c2 = 0, c3 = 0;
  for (int e0 = t; e0 < E_; e0 += 4096) {
    int s0 = sp[e0],        d0 = dp[e0];
    int s1 = sp[e0 + 1024], d1 = dp[e0 + 1024];
    int s2 = sp[e0 + 2048], d2 = dp[e0 + 2048];
    int s3 = sp[e0 + 3072], d3 = dp[e0 + 3072];
    int dr0 = d0 >> 9, dr1 = d1 >> 9, dr2 = d2 >> 9, dr3 = d3 >> 9;
    c0 += (dr0 == 0) + (dr1 == 0) + (dr2 == 0) + (dr3 == 0);
    c1 += (dr0 == 1) + (dr1 == 1) + (dr2 == 1) + (dr3 == 1);
    c2 += (dr0 == 2) + (dr1 == 2) + (dr2 == 2) + (dr3 == 2);
    c3 += (dr0 == 3) + (dr1 == 3) + (dr2 == 3) + (dr3 == 3);
    if (dr0 == r) atomicAdd(&h_in[d0 - lo], 1);
    if (dr1 == r) atomicAdd(&h_in[d1 - lo], 1);
    if (dr2 == r) atomicAdd(&h_in[d2 - lo], 1);
    if (dr3 == r) atomicAdd(&h_in[d3 - lo], 1);
    if ((s0 >> 9) == r) atomicAdd(&h_out[s0 - lo], 1);
    if ((s1 >> 9) == r) atomicAdd(&h_out[s1 - lo], 1);
    if ((s2 >> 9) == r) atomicAdd(&h_out[s2 - lo], 1);
    if ((s3 >> 9) == r) atomicAdd(&h_out[s3 - lo], 1);
  }
  if (c0) atomicAdd(&rtot[0], c0);
  if (c1) atomicAdd(&rtot[1], c1);
  if (c2) atomicAdd(&rtot[2], c2);
  if (c3) atomicAdd(&rtot[3], c3);
  __syncthreads();
  // norms for my range
  if (t < 512) {
    int dv = h_out[t], di = h_in[t];
    norm_s[b * N_ + lo + t] = dv > 0 ? rsqrtf((float)dv) : 0.f;
    norm_d[b * N_ + lo + t] = di > 0 ? rsqrtf((float)di) : 0.f;
  }
  int base = 0;
  if (r > 0) base += rtot[0];
  if (r > 1) base += rtot[1];
  if (r > 2) base += rtot[2];
  // inclusive scan of h_in over 512 elems
  if (t < 512) part[t] = h_in[t];
  __syncthreads();
  for (int off = 1; off < 512; off <<= 1) {
    int x = (t >= off && t < 512) ? part[t - off] : 0;
    __syncthreads();
    if (t < 512) part[t] += x;
    __syncthreads();
  }
  if (t < 512) {
    int st = base + part[t] - h_in[t];   // exclusive start, global
    rowst[t] = st;
    row_ptr[b * (N_ + 1) + lo + t] = st;
    h_in[t] = 0;                          // reuse as fill counter
  }
  if (r == 3 && t == 511) row_ptr[b * (N_ + 1) + N_] = base + part[511];  // = E
  __syncthreads();
  // CSR fill (only edges whose dst is in my range), 4x unrolled
  int* cg = csr + (size_t)b * E_;
  for (int e0 = t; e0 < E_; e0 += 4096) {
    int d0 = dp[e0],        s0 = sp[e0];
    int d1 = dp[e0 + 1024], s1 = sp[e0 + 1024];
    int d2 = dp[e0 + 2048], s2 = sp[e0 + 2048];
    int d3 = dp[e0 + 3072], s3 = sp[e0 + 3072];
    if ((d0 >> 9) == r) { int pos = rowst[d0 - lo] + atomicAdd(&h_in[d0 - lo], 1); cg[pos] = s0; }
    if ((d1 >> 9) == r) { int pos = rowst[d1 - lo] + atomicAdd(&h_in[d1 - lo], 1); cg[pos] = s1; }
    if ((d2 >> 9) == r) { int pos = rowst[d2 - lo] + atomicAdd(&h_in[d2 - lo], 1); cg[pos] = s2; }
    if ((d3 >> 9) == r) { int pos = rowst[d3 - lo] + atomicAdd(&h_in[d3 - lo], 1); cg[pos] = s3; }
  }
}

// ---------------- feat f32 -> bf16 pre-scaled by norm_s (XCD-pinned per graph) ----------------
__global__ __launch_bounds__(256) void k_f2bf_scaled(const float* __restrict__ in,
                                                     const float* __restrict__ norm_s,
                                                     unsigned short* __restrict__ out) {
  int blk = blockIdx.x;
  int b = ((blk >> 10) << 3) | (blk & 7);
  int nb = (blk >> 3) & 127;
  int t = threadIdx.x;
  int node = b * N_ + nb * 16 + (t >> 4);
  int f0 = (t & 15) * 8;
  float ns = norm_s[node];
  const float4* p = (const float4*)(in + (size_t)node * F_ + f0);
  float4 v0 = p[0], v1 = p[1];
  uint4 o;
  o.x = f2bf(v0.x * ns) | (f2bf(v0.y * ns) << 16);
  o.y = f2bf(v0.z * ns) | (f2bf(v0.w * ns) << 16);
  o.z = f2bf(v1.x * ns) | (f2bf(v1.y * ns) << 16);
  o.w = f2bf(v1.z * ns) | (f2bf(v1.w * ns) << 16);
  *(uint4*)(out + (size_t)node * F_ + f0) = o;
}

// ---------------- pack W (f32 [128k][128n]) into MFMA fragment layout, bf16 hi/lo ----------------
__global__ __launch_bounds__(256) void k_packW(const float* __restrict__ W,
                                               unsigned short* __restrict__ wp_hi,
                                               unsigned short* __restrict__ wp_lo) {
  int tid = blockIdx.x * 256 + threadIdx.x;     // 2048 = 32 frags * 64 lanes
  int lane = tid & 63, frag = tid >> 6;         // frag = kt*8 + nt
  if (frag >= 32) return;
  int kt = frag >> 3, nt = frag & 7;
  int k0 = kt * 32 + (lane >> 4) * 8;
  int n = nt * 16 + (lane & 15);
  for (int j = 0; j < 8; j++) {
    float w = W[(size_t)(k0 + j) * 128 + n];
    unsigned int hi = f2bf(w);
    float whi = bf2f(hi);
    unsigned int lo = f2bf(w - whi);
    wp_hi[(size_t)tid * 8 + j] = (unsigned short)hi;
    wp_lo[(size_t)tid * 8 + j] = (unsigned short)lo;
  }
}

// ---------------- FUSED aggregate + MFMA GEMM (transposed) ----------------
// One wave = 16 nodes. Phase 1: lane aggregates features kt*32+kg*8..+8 (kg=lane>>4)
// of node (lane&15) over its CSR row -> lands directly in MFMA B-fragment layout.
// Phase 2: D^T = W^T x agg^T, 64 MFMAs, uint2 epilogue (cr + optional next-layer hs).
// XCD-pinned: blockIdx = (b>>3)*256 + nb*8 + (b&7), nb in [0,32).
// hs_in and hs_out MUST be different buffers (readers/writers overlap across blocks).
template <bool WRITE_HS>
__global__ __launch_bounds__(256) void k_fused(const unsigned short* __restrict__ hs_in,
                                               const int* __restrict__ row_ptr,
                                               const int* __restrict__ csr,
                                               const float* __restrict__ norm_d,
                                               const unsigned short* __restrict__ wp_hi,
                                               const unsigned short* __restrict__ wp_lo,
                                               const float* __restrict__ bias,
                                               unsigned short* __restrict__ cr,
                                               int out_off,
                                               const float* __restrict__ norm_s,
                                               unsigned short* __restrict__ hs_out) {
  int blk = blockIdx.x;
  int b = ((blk >> 8) << 3) | (blk & 7);
  int nb = (blk >> 3) & 31;
  int t = threadIdx.x;
  int wave = t >> 6, lane = t & 63;
  int n = nb * 64 + wave * 16 + (lane & 15);    // local node (one per lane&15)
  int node = b * N_ + n;
  int kg = lane >> 4;

  // ---- phase 1: gather-aggregate 32 features of my node ----
  float acc[4][8];
#pragma unroll
  for (int kt = 0; kt < 4; kt++)
#pragma unroll
    for (int j = 0; j < 8; j++) acc[kt][j] = 0.f;

  int r0 = row_ptr[b * (N_ + 1) + n], r1 = row_ptr[b * (N_ + 1) + n + 1];
  const int* cs = csr + (size_t)b * E_;
  const unsigned short* hbase = hs_in + (size_t)b * N_ * F_ + kg * 8;

#define ACCK(kt, u) { acc[kt][0] += bf2f(u.x); acc[kt][1] += bf2f(u.x >> 16); \
                      acc[kt][2] += bf2f(u.y); acc[kt][3] += bf2f(u.y >> 16); \
                      acc[kt][4] += bf2f(u.z); acc[kt][5] += bf2f(u.z >> 16); \
                      acc[kt][6] += bf2f(u.w); acc[kt][7] += bf2f(u.w >> 16); }
  int e = r0;
  for (; e + 2 <= r1; e += 2) {
    int s0 = cs[e], s1 = cs[e + 1];
    const unsigned short* p0 = hbase + (size_t)s0 * F_;
    const unsigned short* p1 = hbase + (size_t)s1 * F_;
    uint4 u00 = *(const uint4*)(p0);
    uint4 u01 = *(const uint4*)(p0 + 32);
    uint4 u02 = *(const uint4*)(p0 + 64);
    uint4 u03 = *(const uint4*)(p0 + 96);
    uint4 u10 = *(const uint4*)(p1);
    uint4 u11 = *(const uint4*)(p1 + 32);
    uint4 u12 = *(const uint4*)(p1 + 64);
    uint4 u13 = *(const uint4*)(p1 + 96);
    ACCK(0, u00); ACCK(1, u01); ACCK(2, u02); ACCK(3, u03);
    ACCK(0, u10); ACCK(1, u11); ACCK(2, u12); ACCK(3, u13);
  }
  if (e < r1) {
    int s0 = cs[e];
    const unsigned short* p0 = hbase + (size_t)s0 * F_;
    uint4 u00 = *(const uint4*)(p0);
    uint4 u01 = *(const uint4*)(p0 + 32);
    uint4 u02 = *(const uint4*)(p0 + 64);
    uint4 u03 = *(const uint4*)(p0 + 96);
    ACCK(0, u00); ACCK(1, u01); ACCK(2, u02); ACCK(3, u03);
  }
#undef ACCK

  // scale by norm_d, round to bf16 -> B-fragments (bit-identical to unfused path)
  float wd = norm_d[node];
  uint4 afr[4];
#pragma unroll
  for (int kt = 0; kt < 4; kt++) {
    afr[kt].x = f2bf(acc[kt][0] * wd) | (f2bf(acc[kt][1] * wd) << 16);
    afr[kt].y = f2bf(acc[kt][2] * wd) | (f2bf(acc[kt][3] * wd) << 16);
    afr[kt].z = f2bf(acc[kt][4] * wd) | (f2bf(acc[kt][5] * wd) << 16);
    afr[kt].w = f2bf(acc[kt][6] * wd) | (f2bf(acc[kt][7] * wd) << 16);
  }

  // ---- phase 2: GEMM, 64 MFMAs ----
  f32x4 cacc[8];
#pragma unroll
  for (int j = 0; j < 8; j++) cacc[j] = (f32x4){0.f, 0.f, 0.f, 0.f};

#pragma unroll
  for (int kt = 0; kt < 4; ++kt) {
    bf16x8 av = *(const bf16x8*)&afr[kt];
    const unsigned short* bh = wp_hi + ((size_t)(kt * 8) * 64 + lane) * 8;
    const unsigned short* bl = wp_lo + ((size_t)(kt * 8) * 64 + lane) * 8;
#pragma unroll
    for (int nt = 0; nt < 8; ++nt) {
      bf16x8 bhv = *(const bf16x8*)(bh + (size_t)nt * 64 * 8);
      bf16x8 blv = *(const bf16x8*)(bl + (size_t)nt * 64 * 8);
      cacc[nt] = __builtin_amdgcn_mfma_f32_16x16x32_bf16(bhv, av, cacc[nt], 0, 0, 0);
      cacc[nt] = __builtin_amdgcn_mfma_f32_16x16x32_bf16(blv, av, cacc[nt], 0, 0, 0);
    }
  }

  // ---- epilogue: D col = lane&15 -> node (== my node), row = kg*4+q -> feature ----
  int fb = kg * 4;
  float ns0 = 0.f;
  if (WRITE_HS) ns0 = norm_s[node];
#pragma unroll
  for (int nt = 0; nt < 8; ++nt) {
    float4 bv = *(const float4*)(bias + nt * 16 + fb);
    float v0 = cacc[nt][0] + bv.x, v1 = cacc[nt][1] + bv.y;
    float v2 = cacc[nt][2] + bv.z, v3 = cacc[nt][3] + bv.w;
    uint2 p0;
    p0.x = f2bf(v0) | (f2bf(v1) << 16);
    p0.y = f2bf(v2) | (f2bf(v3) << 16);
    *(uint2*)(cr + (size_t)node * C_ + out_off + nt * 16 + fb) = p0;
    if (WRITE_HS) {
      uint2 q0;
      q0.x = f2bf(v0 * ns0) | (f2bf(v1 * ns0) << 16);
      q0.y = f2bf(v2 * ns0) | (f2bf(v3 * ns0) << 16);
      *(uint2*)(hs_out + (size_t)node * F_ + nt * 16 + fb) = q0;
    }
  }
}

// ---------------- score stage 1: y[n] = (cr[n] . Ws) * norm_s[n] ----------------
__global__ __launch_bounds__(256) void k_score_y(const unsigned short* __restrict__ cr,
                                                 const float* __restrict__ Wsc,
                                                 const float* __restrict__ norm_s,
                                                 float* __restrict__ y) {
  int node = blockIdx.x * 4 + (threadIdx.x >> 6);
  int lane = threadIdx.x & 63;
  const unsigned short* row = cr + (size_t)node * C_;
  float acc = 0.f;
  for (int f = lane; f < C_; f += 64) acc += bf2f(row[f]) * Wsc[f];
  for (int off = 32; off > 0; off >>= 1) acc += __shfl_xor(acc, off);
  if (lane == 0) y[node] = acc * norm_s[node];
}

// ---------------- score stage 2: score[n] = norm_d[n] * sum_in y[src] + bs ----------------
__global__ __launch_bounds__(256) void k_score_agg(const float* __restrict__ y,
                                                   const int* __restrict__ row_ptr,
                                                   const int* __restrict__ csr,
                                                   const float* __restrict__ norm_d,
                                                   const float* __restrict__ bs,
                                                   float* __restrict__ score) {
  int node = blockIdx.x * 256 + threadIdx.x;
  int b = node >> 11, n = node & (N_ - 1);
  int r0 = row_ptr[b * (N_ + 1) + n], r1 = row_ptr[b * (N_ + 1) + n + 1];
  const int* cs = csr + (size_t)b * E_;
  float a = 0.f;
  for (int e = r0; e < r1; ++e) a += y[b * N_ + cs[e]];
  score[node] = norm_d[node] * a + bs[0];
}

// ---------------- top-k selection per graph (K=1024 of 2048) ----------------
__global__ __launch_bounds__(256) void k_topk(const float* __restrict__ score,
                                              float* __restrict__ selw,
                                              int* __restrict__ flags) {
  __shared__ unsigned int keys[N_];
  __shared__ int red[256];
  int b = blockIdx.x, t = threadIdx.x;
  for (int i = t; i < N_; i += 256) {
    unsigned u = __float_as_uint(score[b * N_ + i]);
    keys[i] = (u & 0x80000000u) ? ~u : (u | 0x80000000u);
  }
  __syncthreads();
  unsigned prefix = 0;
  for (int bit = 31; bit >= 0; bit--) {
    unsigned cand = prefix | (1u << bit);
    int c = 0;
    for (int i = t; i < N_; i += 256) c += ((keys[i] >> bit) >= (cand >> bit));
    red[t] = c;
    __syncthreads();
    for (int off = 128; off > 0; off >>= 1) { if (t < off) red[t] += red[t + off]; __syncthreads(); }
    if (red[0] >= K_) prefix = cand;
    __syncthreads();
  }
  unsigned T = prefix;
  int c = 0;
  for (int i = t; i < N_; i += 256) c += (keys[i] > T);
  red[t] = c;
  __syncthreads();
  for (int off = 128; off > 0; off >>= 1) { if (t < off) red[t] += red[t + off]; __syncthreads(); }
  int R = K_ - red[0];                          // ties to take, index order
  __syncthreads();
  unsigned kk[8]; int myt = 0;
  for (int j = 0; j < 8; j++) { kk[j] = keys[t * 8 + j]; myt += (kk[j] == T); }
  red[t] = myt;
  __syncthreads();
  for (int off = 1; off < 256; off <<= 1) {
    int x = (t >= off) ? red[t - off] : 0;
    __syncthreads();
    red[t] += x;
    __syncthreads();
  }
  int rank = red[t] - myt;
  for (int j = 0; j < 8; j++) {
    int i = t * 8 + j;
    bool tie = (kk[j] == T);
    bool sel = (kk[j] > T) || (tie && rank < R);
    if (tie) rank++;
    flags[b * N_ + i] = sel ? 1 : 0;
    selw[b * N_ + i] = sel ? tanhf(score[b * N_ + i]) : 0.f;
  }
}

// ---------------- readout partials: sum & max of selected tanh-weighted rows ----------------
__global__ __launch_bounds__(384) void k_readout_part(const unsigned short* __restrict__ cr,
                                                      const float* __restrict__ selw,
                                                      const int* __restrict__ flags,
                                                      float* __restrict__ psum,
                                                      float* __restrict__ pmax) {
  __shared__ int fl[128];
  __shared__ float wv[128];
  int b = blockIdx.x >> 4, ch = blockIdx.x & 15;
  int f = threadIdx.x;
  int n0 = ch * 128;
  if (f < 128) { fl[f] = flags[b * N_ + n0 + f]; wv[f] = selw[b * N_ + n0 + f]; }
  __syncthreads();
  float sum = 0.f, mx = -3.402823466e38f;
  const unsigned short* base = cr + ((size_t)b * N_ + n0) * C_ + f;
  for (int n = 0; n < 128; n++) {
    float v = bf2f(base[(size_t)n * C_]);
    if (fl[n]) { float x = v * wv[n]; sum += x; mx = fmaxf(mx, x); }
  }
  psum[((size_t)b * 16 + ch) * C_ + f] = sum;
  pmax[((size_t)b * 16 + ch) * C_ + f] = mx;
}

__global__ __launch_bounds__(384) void k_readout_red(const float* __restrict__ psum,
                                                     const float* __restrict__ pmax,
                                                     float* __restrict__ g) {
  int b = blockIdx.x, f = threadIdx.x;
  float s = 0.f, m = -3.402823466e38f;
  for (int ch = 0; ch < 16; ch++) {
    s += psum[((size_t)b * 16 + ch) * C_ + f];
    m = fmaxf(m, pmax[((size_t)b * 16 + ch) * C_ + f]);
  }
  g[b * 768 + f] = s * (1.f / K_);
  g[b * 768 + C_ + f] = m;
}

// ---------------- MLP layer 1: h1 = g @ w1 ----------------
__global__ __launch_bounds__(128) void k_mlp1(const float* __restrict__ g,
                                              const float* __restrict__ w1,
                                              float* __restrict__ h1) {
  __shared__ float gr[768];
  int b = blockIdx.x, t = threadIdx.x;
  for (int i = t; i < 768; i += 128) gr[i] = g[b * 768 + i];
  __syncthreads();
  float acc = 0.f;
  for (int k = 0; k < 768; k++) acc += gr[k] * w1[(size_t)k * 128 + t];
  h1[b * 128 + t] = acc;
}

// ---------------- BN + ReLU + mlp_w2 + log_softmax ----------------
__global__ __launch_bounds__(128) void k_mlp2(const float* __restrict__ h1,
                                              const float* __restrict__ bn_g,
                                              const float* __restrict__ bn_b,
                                              const float* __restrict__ w2,
                                              float* __restrict__ out) {
  __shared__ float hn[64][128];
  __shared__ float o[64][10];
  int t = threadIdx.x;   // 128
  float mean = 0.f;
  for (int r = 0; r < 64; r++) mean += h1[r * 128 + t];
  mean *= (1.f / 64.f);
  float var = 0.f;
  for (int r = 0; r < 64; r++) { float d = h1[r * 128 + t] - mean; var += d * d; }
  var *= (1.f / 64.f);
  float sc = bn_g[t] * rsqrtf(var + 1e-5f), sh = bn_b[t];
  for (int r = 0; r < 64; r++) {
    float v = (h1[r * 128 + t] - mean) * sc + sh;
    hn[r][t] = fmaxf(v, 0.f);
  }
  __syncthreads();
  for (int j = 0; j < 5; j++) {
    int idx = t + j * 128;           // 0..639
    int r = idx / 10, c = idx % 10;
    float a = 0.f;
    for (int k = 0; k < 128; k++) a += hn[r][k] * w2[k * 10 + c];
    o[r][c] = a;
  }
  __syncthreads();
  if (t < 64) {
    float mx = -3.402823466e38f;
    for (int c = 0; c < 10; c++) mx = fmaxf(mx, o[t][c]);
    float se = 0.f;
    for (int c = 0; c < 10; c++) se += expf(o[t][c] - mx);
    float l = logf(se);
    for (int c = 0; c < 10; c++) out[t * 10 + c] = o[t][c] - mx - l;
  }
}

extern "C" void kernel_launch(void* const* d_in, const int* in_sizes, int n_in,
                              void* d_out, int out_size, void* d_ws, size_t ws_size,
                              hipStream_t stream) {
  const float* feat = (const float*)d_in[0];
  const int* src = (const int*)d_in[1];
  const int* dst = (const int*)d_in[2];
  const float* W0 = (const float*)d_in[3];  const float* b0 = (const float*)d_in[4];
  const float* W1 = (const float*)d_in[5];  const float* b1 = (const float*)d_in[6];
  const float* W2 = (const float*)d_in[7];  const float* b2 = (const float*)d_in[8];
  const float* Ws = (const float*)d_in[9];  const float* bs = (const float*)d_in[10];
  const float* mw1 = (const float*)d_in[11];
  const float* bng = (const float*)d_in[12];
  const float* bnb = (const float*)d_in[13];
  const float* mw2 = (const float*)d_in[14];
  float* out = (float*)d_out;

  char* p = (char*)d_ws;
  auto alloc = [&](size_t bytes) -> void* {
    void* r = (void*)p;
    p += (bytes + 255) & ~(size_t)255;
    return r;
  };
  int* row_ptr = (int*)alloc((size_t)B_ * (N_ + 1) * 4);
  float* norm_s = (float*)alloc((size_t)NB_ * 4);
  float* norm_d = (float*)alloc((size_t)NB_ * 4);
  int* csr      = (int*)alloc((size_t)B_ * E_ * 4);
  unsigned short* cr  = (unsigned short*)alloc((size_t)NB_ * C_ * 2);
  unsigned short* hs0 = (unsigned short*)alloc((size_t)NB_ * F_ * 2);   // ping
  unsigned short* hs1 = (unsigned short*)alloc((size_t)NB_ * F_ * 2);   // pong
  float* y     = (float*)alloc((size_t)NB_ * 4);
  float* score = (float*)alloc((size_t)NB_ * 4);
  float* selw  = (float*)alloc((size_t)NB_ * 4);
  int* flags   = (int*)alloc((size_t)NB_ * 4);
  float* psum  = (float*)alloc((size_t)B_ * 16 * C_ * 4);
  float* pmax  = (float*)alloc((size_t)B_ * 16 * C_ * 4);
  float* g     = (float*)alloc((size_t)B_ * 768 * 4);
  float* h1    = (float*)alloc((size_t)B_ * 128 * 4);
  unsigned short* wp0h = (unsigned short*)alloc(16384 * 2);
  unsigned short* wp0l = (unsigned short*)alloc(16384 * 2);
  unsigned short* wp1h = (unsigned short*)alloc(16384 * 2);
  unsigned short* wp1l = (unsigned short*)alloc(16384 * 2);
  unsigned short* wp2h = (unsigned short*)alloc(16384 * 2);
  unsigned short* wp2l = (unsigned short*)alloc(16384 * 2);

  // prep: 4 blocks per graph, range-partitioned, no global atomics
  k_prep<<<dim3(B_ * 4), dim3(1024), 0, stream>>>(src, dst, norm_s, norm_d, row_ptr, csr);

  // weight packs: 32 frags * 64 lanes = 2048 threads = 8 blocks
  k_packW<<<dim3(8), dim3(256), 0, stream>>>(W0, wp0h, wp0l);
  k_packW<<<dim3(8), dim3(256), 0, stream>>>(W1, wp1h, wp1l);
  k_packW<<<dim3(8), dim3(256), 0, stream>>>(W2, wp2h, wp2l);

  // hs0 = feat * norm_s (bf16), XCD-pinned
  k_f2bf_scaled<<<dim3(NB_ / 16), dim3(256), 0, stream>>>(feat, norm_s, hs0);

  // fused layers (hs ping-pong: readers and writers must not share a buffer)
  k_fused<true><<<dim3(NB_ / 64), dim3(256), 0, stream>>>(hs0, row_ptr, csr, norm_d,
                                                          wp0h, wp0l, b0, cr, 0, norm_s, hs1);
  k_fused<true><<<dim3(NB_ / 64), dim3(256), 0, stream>>>(hs1, row_ptr, csr, norm_d,
                                                          wp1h, wp1l, b1, cr, 128, norm_s, hs0);
  k_fused<false><<<dim3(NB_ / 64), dim3(256), 0, stream>>>(hs0, row_ptr, csr, norm_d,
                                                           wp2h, wp2l, b2, cr, 256, norm_s, nullptr);

  // SAGPool score
  k_score_y<<<dim3(NB_ / 4), dim3(256), 0, stream>>>(cr, Ws, norm_s, y);
  k_score_agg<<<dim3(NB_ / 256), dim3(256), 0, stream>>>(y, row_ptr, csr, norm_d, bs, score);
  k_topk<<<dim3(B_), dim3(256), 0, stream>>>(score, selw, flags);

  // readout
  k_readout_part<<<dim3(B_ * 16), dim3(384), 0, stream>>>(cr, selw, flags, psum, pmax);
  k_readout_red<<<dim3(B_), dim3(384), 0, stream>>>(psum, pmax, g);

  // MLP
  k_mlp1<<<dim3(B_), dim3(128), 0, stream>>>(g, mw1, h1);
  k_mlp2<<<dim3(1), dim3(128), 0, stream>>>(h1, bng, bnb, mw2, out);
}

// Round 11
// 511.097 us; speedup vs baseline: 1.1030x; 1.1030x over previous
//
#include <hip/hip_runtime.h>
#include <hip/hip_bf16.h>
#include <math.h>

#define B_   64
#define N_   2048
#define E_   32768
#define K_   1024
#define F_   128
#define C_   384
#define NB_  (B_ * N_)

typedef __bf16 bf16x8 __attribute__((ext_vector_type(8)));
typedef float  f32x4  __attribute__((ext_vector_type(4)));

__device__ __forceinline__ float bf2f(unsigned int u) {
  return __uint_as_float(u << 16);   // uses low 16 bits
}
__device__ __forceinline__ unsigned int f2bf(float f) {
  unsigned int x = __float_as_uint(f);
  return (x + 0x7fffu + ((x >> 16) & 1u)) >> 16;   // RNE
}

// ---------------- graph prep: 4 blocks per graph, each owns a 512-node range ----------------
__global__ __launch_bounds__(1024) void k_prep(const int* __restrict__ src,
                                               const int* __restrict__ dst,
                                               float* __restrict__ norm_s,
                                               float* __restrict__ norm_d,
                                               int* __restrict__ row_ptr,
                                               int* __restrict__ csr) {
  __shared__ int h_in[512];      // deg_in for my range, later reused as fill counters
  __shared__ int h_out[512];     // deg_out for my range
  __shared__ int rowst[512];     // row starts (global) for my range
  __shared__ int part[512];      // scan workspace
  __shared__ int rtot[4];        // edges per dst-range (whole graph)
  int b = blockIdx.x >> 2, r = blockIdx.x & 3;
  int lo = r << 9;
  int t = threadIdx.x;
  if (t < 512) { h_in[t] = 0; h_out[t] = 0; }
  if (t < 4) rtot[t] = 0;
  __syncthreads();
  const int* sp = src + (size_t)b * E_;
  const int* dp = dst + (size_t)b * E_;
  int c0 = 0, c1 = 0, c2 = 0, c3 = 0;
  for (int e0 = t; e0 < E_; e0 += 4096) {
    int s0 = sp[e0],        d0 = dp[e0];
    int s1 = sp[e0 + 1024], d1 = dp[e0 + 1024];
    int s2 = sp[e0 + 2048], d2 = dp[e0 + 2048];
    int s3 = sp[e0 + 3072], d3 = dp[e0 + 3072];
    int dr0 = d0 >> 9, dr1 = d1 >> 9, dr2 = d2 >> 9, dr3 = d3 >> 9;
    c0 += (dr0 == 0) + (dr1 == 0) + (dr2 == 0) + (dr3 == 0);
    c1 += (dr0 == 1) + (dr1 == 1) + (dr2 == 1) + (dr3 == 1);
    c2 += (dr0 == 2) + (dr1 == 2) + (dr2 == 2) + (dr3 == 2);
    c3 += (dr0 == 3) + (dr1 == 3) + (dr2 == 3) + (dr3 == 3);
    if (dr0 == r) atomicAdd(&h_in[d0 - lo], 1);
    if (dr1 == r) atomicAdd(&h_in[d1 - lo], 1);
    if (dr2 == r) atomicAdd(&h_in[d2 - lo], 1);
    if (dr3 == r) atomicAdd(&h_in[d3 - lo], 1);
    if ((s0 >> 9) == r) atomicAdd(&h_out[s0 - lo], 1);
    if ((s1 >> 9) == r) atomicAdd(&h_out[s1 - lo], 1);
    if ((s2 >> 9) == r) atomicAdd(&h_out[s2 - lo], 1);
    if ((s3 >> 9) == r) atomicAdd(&h_out[s3 - lo], 1);
  }
  if (c0) atomicAdd(&rtot[0], c0);
  if (c1) atomicAdd(&rtot[1], c1);
  if (c2) atomicAdd(&rtot[2], c2);
  if (c3) atomicAdd(&rtot[3], c3);
  __syncthreads();
  // norms for my range
  if (t < 512) {
    int dv = h_out[t], di = h_in[t];
    norm_s[b * N_ + lo + t] = dv > 0 ? rsqrtf((float)dv) : 0.f;
    norm_d[b * N_ + lo + t] = di > 0 ? rsqrtf((float)di) : 0.f;
  }
  int base = 0;
  if (r > 0) base += rtot[0];
  if (r > 1) base += rtot[1];
  if (r > 2) base += rtot[2];
  // inclusive scan of h_in over 512 elems
  if (t < 512) part[t] = h_in[t];
  __syncthreads();
  for (int off = 1; off < 512; off <<= 1) {
    int x = (t >= off && t < 512) ? part[t - off] : 0;
    __syncthreads();
    if (t < 512) part[t] += x;
    __syncthreads();
  }
  if (t < 512) {
    int st = base + part[t] - h_in[t];   // exclusive start, global
    rowst[t] = st;
    row_ptr[b * (N_ + 1) + lo + t] = st;
    h_in[t] = 0;                          // reuse as fill counter
  }
  if (r == 3 && t == 511) row_ptr[b * (N_ + 1) + N_] = base + part[511];  // = E
  __syncthreads();
  // CSR fill (only edges whose dst is in my range), 4x unrolled
  int* cg = csr + (size_t)b * E_;
  for (int e0 = t; e0 < E_; e0 += 4096) {
    int d0 = dp[e0],        s0 = sp[e0];
    int d1 = dp[e0 + 1024], s1 = sp[e0 + 1024];
    int d2 = dp[e0 + 2048], s2 = sp[e0 + 2048];
    int d3 = dp[e0 + 3072], s3 = sp[e0 + 3072];
    if ((d0 >> 9) == r) { int pos = rowst[d0 - lo] + atomicAdd(&h_in[d0 - lo], 1); cg[pos] = s0; }
    if ((d1 >> 9) == r) { int pos = rowst[d1 - lo] + atomicAdd(&h_in[d1 - lo], 1); cg[pos] = s1; }
    if ((d2 >> 9) == r) { int pos = rowst[d2 - lo] + atomicAdd(&h_in[d2 - lo], 1); cg[pos] = s2; }
    if ((d3 >> 9) == r) { int pos = rowst[d3 - lo] + atomicAdd(&h_in[d3 - lo], 1); cg[pos] = s3; }
  }
}

// ---------------- feat f32 -> bf16 pre-scaled by norm_s (XCD-pinned per graph) ----------------
__global__ __launch_bounds__(256) void k_f2bf_scaled(const float* __restrict__ in,
                                                     const float* __restrict__ norm_s,
                                                     unsigned short* __restrict__ out) {
  int blk = blockIdx.x;
  int b = ((blk >> 10) << 3) | (blk & 7);
  int nb = (blk >> 3) & 127;
  int t = threadIdx.x;
  int node = b * N_ + nb * 16 + (t >> 4);
  int f0 = (t & 15) * 8;
  float ns = norm_s[node];
  const float4* p = (const float4*)(in + (size_t)node * F_ + f0);
  float4 v0 = p[0], v1 = p[1];
  uint4 o;
  o.x = f2bf(v0.x * ns) | (f2bf(v0.y * ns) << 16);
  o.y = f2bf(v0.z * ns) | (f2bf(v0.w * ns) << 16);
  o.z = f2bf(v1.x * ns) | (f2bf(v1.y * ns) << 16);
  o.w = f2bf(v1.z * ns) | (f2bf(v1.w * ns) << 16);
  *(uint4*)(out + (size_t)node * F_ + f0) = o;
}

// ---------------- aggregate: one node per WAVE ----------------
// lane = (es = lane>>4: edge slot, f8 = lane&15: 16B feature slice).
// 4 edges in flight per iteration; trip count wave-uniform (no divergence).
// Final: butterfly-reduce across es groups (shfl_xor 16, 32), lanes 0-15 store.
// XCD-pinned: blockIdx = (b>>3)*4096 + nb*8 + (b&7), nb in [0,512); node = nb*4+wave.
__global__ __launch_bounds__(256) void k_agg(const unsigned short* __restrict__ hs,
                                             const int* __restrict__ row_ptr,
                                             const int* __restrict__ csr,
                                             const float* __restrict__ norm_d,
                                             unsigned short* __restrict__ agg) {
  int blk = blockIdx.x;
  int b = ((blk >> 12) << 3) | (blk & 7);
  int nb = (blk >> 3) & 511;
  int t = threadIdx.x;
  int wave = t >> 6, lane = t & 63;
  int es = lane >> 4, f8 = lane & 15;
  int n = nb * 4 + wave;
  int node = b * N_ + n;
  int r0 = row_ptr[b * (N_ + 1) + n], r1 = row_ptr[b * (N_ + 1) + n + 1];
  const int* cs = csr + (size_t)b * E_;
  const unsigned short* hb = hs + ((size_t)b * N_) * F_ + f8 * 8;
  float a0 = 0.f, a1 = 0.f, a2 = 0.f, a3 = 0.f, a4 = 0.f, a5 = 0.f, a6 = 0.f, a7 = 0.f;
#define ACC8(u) { a0 += bf2f(u.x); a1 += bf2f(u.x >> 16); a2 += bf2f(u.y); a3 += bf2f(u.y >> 16); \
                  a4 += bf2f(u.z); a5 += bf2f(u.z >> 16); a6 += bf2f(u.w); a7 += bf2f(u.w >> 16); }
  int e = r0 + es;
  // 4x unroll: 16 edges per wave-iteration, 4 loads in flight per lane
  for (; e + 12 < r1; e += 16) {
    int s0 = cs[e], s1 = cs[e + 4], s2 = cs[e + 8], s3 = cs[e + 12];
    uint4 u0 = *(const uint4*)(hb + (size_t)s0 * F_);
    uint4 u1 = *(const uint4*)(hb + (size_t)s1 * F_);
    uint4 u2 = *(const uint4*)(hb + (size_t)s2 * F_);
    uint4 u3 = *(const uint4*)(hb + (size_t)s3 * F_);
    ACC8(u0); ACC8(u1); ACC8(u2); ACC8(u3);
  }
  for (; e < r1; e += 4) {
    int s0 = cs[e];
    uint4 u0 = *(const uint4*)(hb + (size_t)s0 * F_);
    ACC8(u0);
  }
#undef ACC8
  // reduce across the 4 edge-slot groups (lanes f8, f8+16, f8+32, f8+48)
#define RED(a) { a += __shfl_xor(a, 16); a += __shfl_xor(a, 32); }
  RED(a0); RED(a1); RED(a2); RED(a3); RED(a4); RED(a5); RED(a6); RED(a7);
#undef RED
  if (es == 0) {
    float wd = norm_d[node];
    uint4 o;
    o.x = f2bf(a0 * wd) | (f2bf(a1 * wd) << 16);
    o.y = f2bf(a2 * wd) | (f2bf(a3 * wd) << 16);
    o.z = f2bf(a4 * wd) | (f2bf(a5 * wd) << 16);
    o.w = f2bf(a6 * wd) | (f2bf(a7 * wd) << 16);
    *(uint4*)(agg + (size_t)node * F_ + f8 * 8) = o;
  }
}

// ---------------- pack W (f32 [128k][128n]) into MFMA fragment layout, bf16 hi/lo ----------------
__global__ __launch_bounds__(256) void k_packW(const float* __restrict__ W,
                                               unsigned short* __restrict__ wp_hi,
                                               unsigned short* __restrict__ wp_lo) {
  int tid = blockIdx.x * 256 + threadIdx.x;     // 2048 = 32 frags * 64 lanes
  int lane = tid & 63, frag = tid >> 6;         // frag = kt*8 + nt
  if (frag >= 32) return;
  int kt = frag >> 3, nt = frag & 7;
  int k0 = kt * 32 + (lane >> 4) * 8;
  int n = nt * 16 + (lane & 15);
  for (int j = 0; j < 8; j++) {
    float w = W[(size_t)(k0 + j) * 128 + n];
    unsigned int hi = f2bf(w);
    float whi = bf2f(hi);
    unsigned int lo = f2bf(w - whi);
    wp_hi[(size_t)tid * 8 + j] = (unsigned short)hi;
    wp_lo[(size_t)tid * 8 + j] = (unsigned short)lo;
  }
}

// ---------------- MFMA GEMM (transposed): D^T = W^T(A) x agg^T(B), 64 nodes/wave ----------------
// Each bhv/blv fragment pair now feeds 8 MFMAs (4 node tiles) -> 2x better MFMA:VMEM ratio.
// XCD-pinned: blockIdx = (b>>3)*64 + nb*8 + (b&7), nb in [0,8); block covers 256 nodes.
template <bool WRITE_HS>
__global__ __launch_bounds__(256) void k_gemm_mfma(const unsigned short* __restrict__ agg,
                                                   const unsigned short* __restrict__ wp_hi,
                                                   const unsigned short* __restrict__ wp_lo,
                                                   const float* __restrict__ bias,
                                                   unsigned short* __restrict__ cr,
                                                   int out_off,
                                                   const float* __restrict__ norm_s,
                                                   unsigned short* __restrict__ hs) {
  int blk = blockIdx.x;
  int b = ((blk >> 6) << 3) | (blk & 7);
  int nb = (blk >> 3) & 7;
  int t = threadIdx.x;
  int wave = t >> 6, lane = t & 63;
  int r0 = b * N_ + nb * 256 + wave * 64;       // 64 nodes per wave
  int arow = lane & 15, kg = lane >> 4;

  f32x4 acc[4][8];
#pragma unroll
  for (int i = 0; i < 4; i++)
#pragma unroll
    for (int j = 0; j < 8; j++) acc[i][j] = (f32x4){0.f, 0.f, 0.f, 0.f};

#pragma unroll
  for (int kt = 0; kt < 4; ++kt) {
    bf16x8 a0 = *(const bf16x8*)(agg + (size_t)(r0 + arow) * F_ + kt * 32 + kg * 8);
    bf16x8 a1 = *(const bf16x8*)(agg + (size_t)(r0 + 16 + arow) * F_ + kt * 32 + kg * 8);
    bf16x8 a2 = *(const bf16x8*)(agg + (size_t)(r0 + 32 + arow) * F_ + kt * 32 + kg * 8);
    bf16x8 a3 = *(const bf16x8*)(agg + (size_t)(r0 + 48 + arow) * F_ + kt * 32 + kg * 8);
    const unsigned short* bh = wp_hi + ((size_t)(kt * 8) * 64 + lane) * 8;
    const unsigned short* bl = wp_lo + ((size_t)(kt * 8) * 64 + lane) * 8;
#pragma unroll
    for (int nt = 0; nt < 8; ++nt) {
      bf16x8 bhv = *(const bf16x8*)(bh + (size_t)nt * 64 * 8);
      bf16x8 blv = *(const bf16x8*)(bl + (size_t)nt * 64 * 8);
      acc[0][nt] = __builtin_amdgcn_mfma_f32_16x16x32_bf16(bhv, a0, acc[0][nt], 0, 0, 0);
      acc[0][nt] = __builtin_amdgcn_mfma_f32_16x16x32_bf16(blv, a0, acc[0][nt], 0, 0, 0);
      acc[1][nt] = __builtin_amdgcn_mfma_f32_16x16x32_bf16(bhv, a1, acc[1][nt], 0, 0, 0);
      acc[1][nt] = __builtin_amdgcn_mfma_f32_16x16x32_bf16(blv, a1, acc[1][nt], 0, 0, 0);
      acc[2][nt] = __builtin_amdgcn_mfma_f32_16x16x32_bf16(bhv, a2, acc[2][nt], 0, 0, 0);
      acc[2][nt] = __builtin_amdgcn_mfma_f32_16x16x32_bf16(blv, a2, acc[2][nt], 0, 0, 0);
      acc[3][nt] = __builtin_amdgcn_mfma_f32_16x16x32_bf16(bhv, a3, acc[3][nt], 0, 0, 0);
      acc[3][nt] = __builtin_amdgcn_mfma_f32_16x16x32_bf16(blv, a3, acc[3][nt], 0, 0, 0);
    }
  }

  // D layout: col = lane&15 -> node (within tile i); row = kg*4+q -> feature (within nt tile)
  int fb = kg * 4;
#pragma unroll
  for (int i = 0; i < 4; ++i) {
    int node = r0 + i * 16 + (lane & 15);
    float ns0 = 0.f;
    if (WRITE_HS) ns0 = norm_s[node];
#pragma unroll
    for (int nt = 0; nt < 8; ++nt) {
      float4 bv = *(const float4*)(bias + nt * 16 + fb);
      float v0 = acc[i][nt][0] + bv.x, v1 = acc[i][nt][1] + bv.y;
      float v2 = acc[i][nt][2] + bv.z, v3 = acc[i][nt][3] + bv.w;
      uint2 p0;
      p0.x = f2bf(v0) | (f2bf(v1) << 16);
      p0.y = f2bf(v2) | (f2bf(v3) << 16);
      *(uint2*)(cr + (size_t)node * C_ + out_off + nt * 16 + fb) = p0;
      if (WRITE_HS) {
        uint2 q0;
        q0.x = f2bf(v0 * ns0) | (f2bf(v1 * ns0) << 16);
        q0.y = f2bf(v2 * ns0) | (f2bf(v3 * ns0) << 16);
        *(uint2*)(hs + (size_t)node * F_ + nt * 16 + fb) = q0;
      }
    }
  }
}

// ---------------- score stage 1: y[n] = (cr[n] . Ws) * norm_s[n] ----------------
__global__ __launch_bounds__(256) void k_score_y(const unsigned short* __restrict__ cr,
                                                 const float* __restrict__ Wsc,
                                                 const float* __restrict__ norm_s,
                                                 float* __restrict__ y) {
  int node = blockIdx.x * 4 + (threadIdx.x >> 6);
  int lane = threadIdx.x & 63;
  const unsigned short* row = cr + (size_t)node * C_;
  float acc = 0.f;
  for (int f = lane; f < C_; f += 64) acc += bf2f(row[f]) * Wsc[f];
  for (int off = 32; off > 0; off >>= 1) acc += __shfl_xor(acc, off);
  if (lane == 0) y[node] = acc * norm_s[node];
}

// ---------------- score stage 2: score[n] = norm_d[n] * sum_in y[src] + bs ----------------
__global__ __launch_bounds__(256) void k_score_agg(const float* __restrict__ y,
                                                   const int* __restrict__ row_ptr,
                                                   const int* __restrict__ csr,
                                                   const float* __restrict__ norm_d,
                                                   const float* __restrict__ bs,
                                                   float* __restrict__ score) {
  int node = blockIdx.x * 256 + threadIdx.x;
  int b = node >> 11, n = node & (N_ - 1);
  int r0 = row_ptr[b * (N_ + 1) + n], r1 = row_ptr[b * (N_ + 1) + n + 1];
  const int* cs = csr + (size_t)b * E_;
  float a = 0.f;
  for (int e = r0; e < r1; ++e) a += y[b * N_ + cs[e]];
  score[node] = norm_d[node] * a + bs[0];
}

// ---------------- top-k selection per graph (K=1024 of 2048) ----------------
__global__ __launch_bounds__(256) void k_topk(const float* __restrict__ score,
                                              float* __restrict__ selw,
                                              int* __restrict__ flags) {
  __shared__ unsigned int keys[N_];
  __shared__ int red[256];
  int b = blockIdx.x, t = threadIdx.x;
  for (int i = t; i < N_; i += 256) {
    unsigned u = __float_as_uint(score[b * N_ + i]);
    keys[i] = (u & 0x80000000u) ? ~u : (u | 0x80000000u);
  }
  __syncthreads();
  unsigned prefix = 0;
  for (int bit = 31; bit >= 0; bit--) {
    unsigned cand = prefix | (1u << bit);
    int c = 0;
    for (int i = t; i < N_; i += 256) c += ((keys[i] >> bit) >= (cand >> bit));
    red[t] = c;
    __syncthreads();
    for (int off = 128; off > 0; off >>= 1) { if (t < off) red[t] += red[t + off]; __syncthreads(); }
    if (red[0] >= K_) prefix = cand;
    __syncthreads();
  }
  unsigned T = prefix;
  int c = 0;
  for (int i = t; i < N_; i += 256) c += (keys[i] > T);
  red[t] = c;
  __syncthreads();
  for (int off = 128; off > 0; off >>= 1) { if (t < off) red[t] += red[t + off]; __syncthreads(); }
  int R = K_ - red[0];                          // ties to take, index order
  __syncthreads();
  unsigned kk[8]; int myt = 0;
  for (int j = 0; j < 8; j++) { kk[j] = keys[t * 8 + j]; myt += (kk[j] == T); }
  red[t] = myt;
  __syncthreads();
  for (int off = 1; off < 256; off <<= 1) {
    int x = (t >= off) ? red[t - off] : 0;
    __syncthreads();
    red[t] += x;
    __syncthreads();
  }
  int rank = red[t] - myt;
  for (int j = 0; j < 8; j++) {
    int i = t * 8 + j;
    bool tie = (kk[j] == T);
    bool sel = (kk[j] > T) || (tie && rank < R);
    if (tie) rank++;
    flags[b * N_ + i] = sel ? 1 : 0;
    selw[b * N_ + i] = sel ? tanhf(score[b * N_ + i]) : 0.f;
  }
}

// ---------------- readout partials: sum & max of selected tanh-weighted rows ----------------
__global__ __launch_bounds__(384) void k_readout_part(const unsigned short* __restrict__ cr,
                                                      const float* __restrict__ selw,
                                                      const int* __restrict__ flags,
                                                      float* __restrict__ psum,
                                                      float* __restrict__ pmax) {
  __shared__ int fl[128];
  __shared__ float wv[128];
  int b = blockIdx.x >> 4, ch = blockIdx.x & 15;
  int f = threadIdx.x;
  int n0 = ch * 128;
  if (f < 128) { fl[f] = flags[b * N_ + n0 + f]; wv[f] = selw[b * N_ + n0 + f]; }
  __syncthreads();
  float sum = 0.f, mx = -3.402823466e38f;
  const unsigned short* base = cr + ((size_t)b * N_ + n0) * C_ + f;
  for (int n = 0; n < 128; n++) {
    float v = bf2f(base[(size_t)n * C_]);
    if (fl[n]) { float x = v * wv[n]; sum += x; mx = fmaxf(mx, x); }
  }
  psum[((size_t)b * 16 + ch) * C_ + f] = sum;
  pmax[((size_t)b * 16 + ch) * C_ + f] = mx;
}

__global__ __launch_bounds__(384) void k_readout_red(const float* __restrict__ psum,
                                                     const float* __restrict__ pmax,
                                                     float* __restrict__ g) {
  int b = blockIdx.x, f = threadIdx.x;
  float s = 0.f, m = -3.402823466e38f;
  for (int ch = 0; ch < 16; ch++) {
    s += psum[((size_t)b * 16 + ch) * C_ + f];
    m = fmaxf(m, pmax[((size_t)b * 16 + ch) * C_ + f]);
  }
  g[b * 768 + f] = s * (1.f / K_);
  g[b * 768 + C_ + f] = m;
}

// ---------------- MLP layer 1: h1 = g @ w1 ----------------
__global__ __launch_bounds__(128) void k_mlp1(const float* __restrict__ g,
                                              const float* __restrict__ w1,
                                              float* __restrict__ h1) {
  __shared__ float gr[768];
  int b = blockIdx.x, t = threadIdx.x;
  for (int i = t; i < 768; i += 128) gr[i] = g[b * 768 + i];
  __syncthreads();
  float acc = 0.f;
  for (int k = 0; k < 768; k++) acc += gr[k] * w1[(size_t)k * 128 + t];
  h1[b * 128 + t] = acc;
}

// ---------------- BN + ReLU + mlp_w2 + log_softmax ----------------
__global__ __launch_bounds__(128) void k_mlp2(const float* __restrict__ h1,
                                              const float* __restrict__ bn_g,
                                              const float* __restrict__ bn_b,
                                              const float* __restrict__ w2,
                                              float* __restrict__ out) {
  __shared__ float hn[64][128];
  __shared__ float o[64][10];
  int t = threadIdx.x;   // 128
  float mean = 0.f;
  for (int r = 0; r < 64; r++) mean += h1[r * 128 + t];
  mean *= (1.f / 64.f);
  float var = 0.f;
  for (int r = 0; r < 64; r++) { float d = h1[r * 128 + t] - mean; var += d * d; }
  var *= (1.f / 64.f);
  float sc = bn_g[t] * rsqrtf(var + 1e-5f), sh = bn_b[t];
  for (int r = 0; r < 64; r++) {
    float v = (h1[r * 128 + t] - mean) * sc + sh;
    hn[r][t] = fmaxf(v, 0.f);
  }
  __syncthreads();
  for (int j = 0; j < 5; j++) {
    int idx = t + j * 128;           // 0..639
    int r = idx / 10, c = idx % 10;
    float a = 0.f;
    for (int k = 0; k < 128; k++) a += hn[r][k] * w2[k * 10 + c];
    o[r][c] = a;
  }
  __syncthreads();
  if (t < 64) {
    float mx = -3.402823466e38f;
    for (int c = 0; c < 10; c++) mx = fmaxf(mx, o[t][c]);
    float se = 0.f;
    for (int c = 0; c < 10; c++) se += expf(o[t][c] - mx);
    float l = logf(se);
    for (int c = 0; c < 10; c++) out[t * 10 + c] = o[t][c] - mx - l;
  }
}

extern "C" void kernel_launch(void* const* d_in, const int* in_sizes, int n_in,
                              void* d_out, int out_size, void* d_ws, size_t ws_size,
                              hipStream_t stream) {
  const float* feat = (const float*)d_in[0];
  const int* src = (const int*)d_in[1];
  const int* dst = (const int*)d_in[2];
  const float* W0 = (const float*)d_in[3];  const float* b0 = (const float*)d_in[4];
  const float* W1 = (const float*)d_in[5];  const float* b1 = (const float*)d_in[6];
  const float* W2 = (const float*)d_in[7];  const float* b2 = (const float*)d_in[8];
  const float* Ws = (const float*)d_in[9];  const float* bs = (const float*)d_in[10];
  const float* mw1 = (const float*)d_in[11];
  const float* bng = (const float*)d_in[12];
  const float* bnb = (const float*)d_in[13];
  const float* mw2 = (const float*)d_in[14];
  float* out = (float*)d_out;

  char* p = (char*)d_ws;
  auto alloc = [&](size_t bytes) -> void* {
    void* r = (void*)p;
    p += (bytes + 255) & ~(size_t)255;
    return r;
  };
  int* row_ptr = (int*)alloc((size_t)B_ * (N_ + 1) * 4);
  float* norm_s = (float*)alloc((size_t)NB_ * 4);
  float* norm_d = (float*)alloc((size_t)NB_ * 4);
  int* csr      = (int*)alloc((size_t)B_ * E_ * 4);
  unsigned short* cr  = (unsigned short*)alloc((size_t)NB_ * C_ * 2);
  unsigned short* agg = (unsigned short*)alloc((size_t)NB_ * F_ * 2);   // A buffer
  unsigned short* hsb = (unsigned short*)alloc((size_t)NB_ * F_ * 2);   // H buffer
  float* y     = (float*)alloc((size_t)NB_ * 4);
  float* score = (float*)alloc((size_t)NB_ * 4);
  float* selw  = (float*)alloc((size_t)NB_ * 4);
  int* flags   = (int*)alloc((size_t)NB_ * 4);
  float* psum  = (float*)alloc((size_t)B_ * 16 * C_ * 4);
  float* pmax  = (float*)alloc((size_t)B_ * 16 * C_ * 4);
  float* g     = (float*)alloc((size_t)B_ * 768 * 4);
  float* h1    = (float*)alloc((size_t)B_ * 128 * 4);
  unsigned short* wp0h = (unsigned short*)alloc(16384 * 2);
  unsigned short* wp0l = (unsigned short*)alloc(16384 * 2);
  unsigned short* wp1h = (unsigned short*)alloc(16384 * 2);
  unsigned short* wp1l = (unsigned short*)alloc(16384 * 2);
  unsigned short* wp2h = (unsigned short*)alloc(16384 * 2);
  unsigned short* wp2l = (unsigned short*)alloc(16384 * 2);

  // prep: 4 blocks per graph, range-partitioned, no global atomics
  k_prep<<<dim3(B_ * 4), dim3(1024), 0, stream>>>(src, dst, norm_s, norm_d, row_ptr, csr);

  // weight packs: 32 frags * 64 lanes = 2048 threads = 8 blocks
  k_packW<<<dim3(8), dim3(256), 0, stream>>>(W0, wp0h, wp0l);
  k_packW<<<dim3(8), dim3(256), 0, stream>>>(W1, wp1h, wp1l);
  k_packW<<<dim3(8), dim3(256), 0, stream>>>(W2, wp2h, wp2l);

  // hs0 = feat * norm_s (bf16), XCD-pinned
  k_f2bf_scaled<<<dim3(NB_ / 16), dim3(256), 0, stream>>>(feat, norm_s, hsb);

  // layer 0: agg(hs) -> A; GEMM -> cr[:,0:128] + hs' -> H
  k_agg<<<dim3(NB_ / 4), dim3(256), 0, stream>>>(hsb, row_ptr, csr, norm_d, agg);
  k_gemm_mfma<true><<<dim3(NB_ / 256), dim3(256), 0, stream>>>(agg, wp0h, wp0l, b0, cr, 0, norm_s, hsb);
  // layer 1
  k_agg<<<dim3(NB_ / 4), dim3(256), 0, stream>>>(hsb, row_ptr, csr, norm_d, agg);
  k_gemm_mfma<true><<<dim3(NB_ / 256), dim3(256), 0, stream>>>(agg, wp1h, wp1l, b1, cr, 128, norm_s, hsb);
  // layer 2 (no hs needed afterwards)
  k_agg<<<dim3(NB_ / 4), dim3(256), 0, stream>>>(hsb, row_ptr, csr, norm_d, agg);
  k_gemm_mfma<false><<<dim3(NB_ / 256), dim3(256), 0, stream>>>(agg, wp2h, wp2l, b2, cr, 256, norm_s, nullptr);

  // SAGPool score
  k_score_y<<<dim3(NB_ / 4), dim3(256), 0, stream>>>(cr, Ws, norm_s, y);
  k_score_agg<<<dim3(NB_ / 256), dim3(256), 0, stream>>>(y, row_ptr, csr, norm_d, bs, score);
  k_topk<<<dim3(B_), dim3(256), 0, stream>>>(score, selw, flags);

  // readout
  k_readout_part<<<dim3(B_ * 16), dim3(384), 0, stream>>>(cr, selw, flags, psum, pmax);
  k_readout_red<<<dim3(B_), dim3(384), 0, stream>>>(psum, pmax, g);

  // MLP
  k_mlp1<<<dim3(B_), dim3(128), 0, stream>>>(g, mw1, h1);
  k_mlp2<<<dim3(1), dim3(128), 0, stream>>>(h1, bng, bnb, mw2, out);
}

// Round 12
// 499.631 us; speedup vs baseline: 1.1283x; 1.0229x over previous
//
#include <hip/hip_runtime.h>
#include <hip/hip_bf16.h>
#include <math.h>

#define B_   64
#define N_   2048
#define E_   32768
#define K_   1024
#define F_   128
#define C_   384
#define NB_  (B_ * N_)

typedef __bf16 bf16x8 __attribute__((ext_vector_type(8)));
typedef float  f32x4  __attribute__((ext_vector_type(4)));

__device__ __forceinline__ float bf2f(unsigned int u) {
  return __uint_as_float(u << 16);   // uses low 16 bits
}
__device__ __forceinline__ unsigned int f2bf(float f) {
  unsigned int x = __float_as_uint(f);
  return (x + 0x7fffu + ((x >> 16) & 1u)) >> 16;   // RNE
}
// LDS tile index: row-major [128][128] shorts with XOR swizzle (bank-conflict fix).
// 8-short granule XOR keeps uint2/uint4 accesses aligned and contiguous.
__device__ __forceinline__ int swz(int row, int scol) {
  return (row * F_ + scol) ^ ((row & 7) << 3);
}

// ---------------- graph prep: 4 blocks per graph, each owns a 512-node range ----------------
__global__ __launch_bounds__(1024) void k_prep(const int* __restrict__ src,
                                               const int* __restrict__ dst,
                                               float* __restrict__ norm_s,
                                               float* __restrict__ norm_d,
                                               int* __restrict__ row_ptr,
                                               int* __restrict__ csr) {
  __shared__ int h_in[512];      // deg_in for my range, later reused as fill counters
  __shared__ int h_out[512];     // deg_out for my range
  __shared__ int rowst[512];     // row starts (global) for my range
  __shared__ int part[512];      // scan workspace
  __shared__ int rtot[4];        // edges per dst-range (whole graph)
  int b = blockIdx.x >> 2, r = blockIdx.x & 3;
  int lo = r << 9;
  int t = threadIdx.x;
  if (t < 512) { h_in[t] = 0; h_out[t] = 0; }
  if (t < 4) rtot[t] = 0;
  __syncthreads();
  const int* sp = src + (size_t)b * E_;
  const int* dp = dst + (size_t)b * E_;
  int c0 = 0, c1 = 0, c2 = 0, c3 = 0;
  for (int e0 = t; e0 < E_; e0 += 4096) {
    int s0 = sp[e0],        d0 = dp[e0];
    int s1 = sp[e0 + 1024], d1 = dp[e0 + 1024];
    int s2 = sp[e0 + 2048], d2 = dp[e0 + 2048];
    int s3 = sp[e0 + 3072], d3 = dp[e0 + 3072];
    int dr0 = d0 >> 9, dr1 = d1 >> 9, dr2 = d2 >> 9, dr3 = d3 >> 9;
    c0 += (dr0 == 0) + (dr1 == 0) + (dr2 == 0) + (dr3 == 0);
    c1 += (dr0 == 1) + (dr1 == 1) + (dr2 == 1) + (dr3 == 1);
    c2 += (dr0 == 2) + (dr1 == 2) + (dr2 == 2) + (dr3 == 2);
    c3 += (dr0 == 3) + (dr1 == 3) + (dr2 == 3) + (dr3 == 3);
    if (dr0 == r) atomicAdd(&h_in[d0 - lo], 1);
    if (dr1 == r) atomicAdd(&h_in[d1 - lo], 1);
    if (dr2 == r) atomicAdd(&h_in[d2 - lo], 1);
    if (dr3 == r) atomicAdd(&h_in[d3 - lo], 1);
    if ((s0 >> 9) == r) atomicAdd(&h_out[s0 - lo], 1);
    if ((s1 >> 9) == r) atomicAdd(&h_out[s1 - lo], 1);
    if ((s2 >> 9) == r) atomicAdd(&h_out[s2 - lo], 1);
    if ((s3 >> 9) == r) atomicAdd(&h_out[s3 - lo], 1);
  }
  if (c0) atomicAdd(&rtot[0], c0);
  if (c1) atomicAdd(&rtot[1], c1);
  if (c2) atomicAdd(&rtot[2], c2);
  if (c3) atomicAdd(&rtot[3], c3);
  __syncthreads();
  // norms for my range
  if (t < 512) {
    int dv = h_out[t], di = h_in[t];
    norm_s[b * N_ + lo + t] = dv > 0 ? rsqrtf((float)dv) : 0.f;
    norm_d[b * N_ + lo + t] = di > 0 ? rsqrtf((float)di) : 0.f;
  }
  int base = 0;
  if (r > 0) base += rtot[0];
  if (r > 1) base += rtot[1];
  if (r > 2) base += rtot[2];
  // inclusive scan of h_in over 512 elems
  if (t < 512) part[t] = h_in[t];
  __syncthreads();
  for (int off = 1; off < 512; off <<= 1) {
    int x = (t >= off && t < 512) ? part[t - off] : 0;
    __syncthreads();
    if (t < 512) part[t] += x;
    __syncthreads();
  }
  if (t < 512) {
    int st = base + part[t] - h_in[t];   // exclusive start, global
    rowst[t] = st;
    row_ptr[b * (N_ + 1) + lo + t] = st;
    h_in[t] = 0;                          // reuse as fill counter
  }
  if (r == 3 && t == 511) row_ptr[b * (N_ + 1) + N_] = base + part[511];  // = E
  __syncthreads();
  // CSR fill (only edges whose dst is in my range), 4x unrolled
  int* cg = csr + (size_t)b * E_;
  for (int e0 = t; e0 < E_; e0 += 4096) {
    int d0 = dp[e0],        s0 = sp[e0];
    int d1 = dp[e0 + 1024], s1 = sp[e0 + 1024];
    int d2 = dp[e0 + 2048], s2 = sp[e0 + 2048];
    int d3 = dp[e0 + 3072], s3 = sp[e0 + 3072];
    if ((d0 >> 9) == r) { int pos = rowst[d0 - lo] + atomicAdd(&h_in[d0 - lo], 1); cg[pos] = s0; }
    if ((d1 >> 9) == r) { int pos = rowst[d1 - lo] + atomicAdd(&h_in[d1 - lo], 1); cg[pos] = s1; }
    if ((d2 >> 9) == r) { int pos = rowst[d2 - lo] + atomicAdd(&h_in[d2 - lo], 1); cg[pos] = s2; }
    if ((d3 >> 9) == r) { int pos = rowst[d3 - lo] + atomicAdd(&h_in[d3 - lo], 1); cg[pos] = s3; }
  }
}

// ---------------- feat f32 -> bf16 pre-scaled by norm_s (XCD-pinned per graph) ----------------
__global__ __launch_bounds__(256) void k_f2bf_scaled(const float* __restrict__ in,
                                                     const float* __restrict__ norm_s,
                                                     unsigned short* __restrict__ out) {
  int blk = blockIdx.x;
  int b = ((blk >> 10) << 3) | (blk & 7);
  int nb = (blk >> 3) & 127;
  int t = threadIdx.x;
  int node = b * N_ + nb * 16 + (t >> 4);
  int f0 = (t & 15) * 8;
  float ns = norm_s[node];
  const float4* p = (const float4*)(in + (size_t)node * F_ + f0);
  float4 v0 = p[0], v1 = p[1];
  uint4 o;
  o.x = f2bf(v0.x * ns) | (f2bf(v0.y * ns) << 16);
  o.y = f2bf(v0.z * ns) | (f2bf(v0.w * ns) << 16);
  o.z = f2bf(v1.x * ns) | (f2bf(v1.y * ns) << 16);
  o.w = f2bf(v1.z * ns) | (f2bf(v1.w * ns) << 16);
  *(uint4*)(out + (size_t)node * F_ + f0) = o;
}

// ---------------- pack W (f32 [128k][128n]) into MFMA fragment layout, bf16 hi/lo ----------------
__global__ __launch_bounds__(256) void k_packW(const float* __restrict__ W,
                                               unsigned short* __restrict__ wp_hi,
                                               unsigned short* __restrict__ wp_lo) {
  int tid = blockIdx.x * 256 + threadIdx.x;     // 2048 = 32 frags * 64 lanes
  int lane = tid & 63, frag = tid >> 6;         // frag = kt*8 + nt
  if (frag >= 32) return;
  int kt = frag >> 3, nt = frag & 7;
  int k0 = kt * 32 + (lane >> 4) * 8;
  int n = nt * 16 + (lane & 15);
  for (int j = 0; j < 8; j++) {
    float w = W[(size_t)(k0 + j) * 128 + n];
    unsigned int hi = f2bf(w);
    float whi = bf2f(hi);
    unsigned int lo = f2bf(w - whi);
    wp_hi[(size_t)tid * 8 + j] = (unsigned short)hi;
    wp_lo[(size_t)tid * 8 + j] = (unsigned short)lo;
  }
}

// ---------------- FUSED layer: aggregate -> LDS -> MFMA GEMM -> coalesced epilogue ----------------
// Block = 128 nodes, 256 threads, XCD-pinned: blockIdx = (b>>3)*128 + nb*8 + (b&7), nb in [0,16).
// Phase 1 (R9 k_agg pattern): 16 lanes/node, 8-deep gathers, result to swizzled LDS.
// Phase 2 (R9 gemm): D^T = W^T x agg^T from LDS fragments. Each wave reads ONLY its own
// 32 rows of As, so after its MFMAs it can reuse its As region for epilogue staging
// without further barriers.
// Epilogue: bias folded into acc; stage bf16 tiles in LDS; write cr (and hs) as
// 256B-contiguous row chunks (full-line stores).
template <bool WRITE_HS>
__global__ __launch_bounds__(256) void k_layer(const unsigned short* __restrict__ hs_in,
                                               const int* __restrict__ row_ptr,
                                               const int* __restrict__ csr,
                                               const float* __restrict__ norm_d,
                                               const unsigned short* __restrict__ wp_hi,
                                               const unsigned short* __restrict__ wp_lo,
                                               const float* __restrict__ bias,
                                               unsigned short* __restrict__ cr,
                                               int out_off,
                                               const float* __restrict__ norm_s,
                                               unsigned short* __restrict__ hs_out) {
  __shared__ unsigned short As[128 * F_];       // 32 KB
  int blk = blockIdx.x;
  int b = ((blk >> 7) << 3) | (blk & 7);
  int nb = (blk >> 3) & 15;
  int t = threadIdx.x;
  int base_n = nb * 128;

  // ---- phase 1: aggregate 128 nodes into LDS (8 passes x 16 nodes) ----
  {
    int nl = t >> 4, f8 = t & 15;
    const int* cs = csr + (size_t)b * E_;
    const unsigned short* hb = hs_in + (size_t)b * N_ * F_ + f8 * 8;
#define ACC8(u) { a0 += bf2f(u.x); a1 += bf2f(u.x >> 16); a2 += bf2f(u.y); a3 += bf2f(u.y >> 16); \
                  a4 += bf2f(u.z); a5 += bf2f(u.z >> 16); a6 += bf2f(u.w); a7 += bf2f(u.w >> 16); }
    for (int p = 0; p < 8; ++p) {
      int nloc = p * 16 + nl;
      int n = base_n + nloc;
      int node = b * N_ + n;
      int r0 = row_ptr[b * (N_ + 1) + n], r1 = row_ptr[b * (N_ + 1) + n + 1];
      float a0 = 0.f, a1 = 0.f, a2 = 0.f, a3 = 0.f, a4 = 0.f, a5 = 0.f, a6 = 0.f, a7 = 0.f;
      int e = r0;
      for (; e + 8 <= r1; e += 8) {
        int s0 = cs[e],     s1 = cs[e + 1], s2 = cs[e + 2], s3 = cs[e + 3];
        int s4 = cs[e + 4], s5 = cs[e + 5], s6 = cs[e + 6], s7 = cs[e + 7];
        uint4 u0 = *(const uint4*)(hb + (size_t)s0 * F_);
        uint4 u1 = *(const uint4*)(hb + (size_t)s1 * F_);
        uint4 u2 = *(const uint4*)(hb + (size_t)s2 * F_);
        uint4 u3 = *(const uint4*)(hb + (size_t)s3 * F_);
        uint4 u4 = *(const uint4*)(hb + (size_t)s4 * F_);
        uint4 u5 = *(const uint4*)(hb + (size_t)s5 * F_);
        uint4 u6 = *(const uint4*)(hb + (size_t)s6 * F_);
        uint4 u7 = *(const uint4*)(hb + (size_t)s7 * F_);
        ACC8(u0); ACC8(u1); ACC8(u2); ACC8(u3);
        ACC8(u4); ACC8(u5); ACC8(u6); ACC8(u7);
      }
      for (; e < r1; ++e) {
        int s0 = cs[e];
        uint4 u0 = *(const uint4*)(hb + (size_t)s0 * F_);
        ACC8(u0);
      }
      float wd = norm_d[node];
      uint4 o;
      o.x = f2bf(a0 * wd) | (f2bf(a1 * wd) << 16);
      o.y = f2bf(a2 * wd) | (f2bf(a3 * wd) << 16);
      o.z = f2bf(a4 * wd) | (f2bf(a5 * wd) << 16);
      o.w = f2bf(a6 * wd) | (f2bf(a7 * wd) << 16);
      *(uint4*)&As[swz(nloc, f8 * 8)] = o;
    }
#undef ACC8
  }
  __syncthreads();

  // ---- phase 2: GEMM from LDS ----
  int wave = t >> 6, lane = t & 63;
  int rl0 = wave * 32;
  int arow = lane & 15, kg = lane >> 4;

  f32x4 acc[2][8];
#pragma unroll
  for (int i = 0; i < 2; i++)
#pragma unroll
    for (int j = 0; j < 8; j++) acc[i][j] = (f32x4){0.f, 0.f, 0.f, 0.f};

#pragma unroll
  for (int kt = 0; kt < 4; ++kt) {
    bf16x8 a0 = *(const bf16x8*)&As[swz(rl0 + arow, kt * 32 + kg * 8)];
    bf16x8 a1 = *(const bf16x8*)&As[swz(rl0 + 16 + arow, kt * 32 + kg * 8)];
    const unsigned short* bh = wp_hi + ((size_t)(kt * 8) * 64 + lane) * 8;
    const unsigned short* bl = wp_lo + ((size_t)(kt * 8) * 64 + lane) * 8;
#pragma unroll
    for (int nt = 0; nt < 8; ++nt) {
      bf16x8 bhv = *(const bf16x8*)(bh + (size_t)nt * 64 * 8);
      bf16x8 blv = *(const bf16x8*)(bl + (size_t)nt * 64 * 8);
      acc[0][nt] = __builtin_amdgcn_mfma_f32_16x16x32_bf16(bhv, a0, acc[0][nt], 0, 0, 0);
      acc[0][nt] = __builtin_amdgcn_mfma_f32_16x16x32_bf16(blv, a0, acc[0][nt], 0, 0, 0);
      acc[1][nt] = __builtin_amdgcn_mfma_f32_16x16x32_bf16(bhv, a1, acc[1][nt], 0, 0, 0);
      acc[1][nt] = __builtin_amdgcn_mfma_f32_16x16x32_bf16(blv, a1, acc[1][nt], 0, 0, 0);
    }
  }

  // ---- epilogue: fold bias, stage to own As region, write coalesced ----
  // D layout: col = lane&15 -> node row (rl0+arow / +16), row = kg*4+q -> feature nt*16+kg*4+q
  int fb = kg * 4;
  int n0l = rl0 + arow, n1l = rl0 + 16 + arow;
#pragma unroll
  for (int nt = 0; nt < 8; ++nt) {
    float4 bv = *(const float4*)(bias + nt * 16 + fb);
    acc[0][nt][0] += bv.x; acc[0][nt][1] += bv.y; acc[0][nt][2] += bv.z; acc[0][nt][3] += bv.w;
    acc[1][nt][0] += bv.x; acc[1][nt][1] += bv.y; acc[1][nt][2] += bv.z; acc[1][nt][3] += bv.w;
    uint2 p0, p1;
    p0.x = f2bf(acc[0][nt][0]) | (f2bf(acc[0][nt][1]) << 16);
    p0.y = f2bf(acc[0][nt][2]) | (f2bf(acc[0][nt][3]) << 16);
    p1.x = f2bf(acc[1][nt][0]) | (f2bf(acc[1][nt][1]) << 16);
    p1.y = f2bf(acc[1][nt][2]) | (f2bf(acc[1][nt][3]) << 16);
    *(uint2*)&As[swz(n0l, nt * 16 + fb)] = p0;
    *(uint2*)&As[swz(n1l, nt * 16 + fb)] = p1;
  }
  // write cr: own 32 rows, 4 rows x 16 chunks per iteration (256B contiguous per row)
  int rrow = lane >> 4, chunk = lane & 15;
#pragma unroll
  for (int it = 0; it < 8; ++it) {
    int rl = rl0 + it * 4 + rrow;
    uint4 vv = *(const uint4*)&As[swz(rl, chunk * 8)];
    *(uint4*)(cr + (size_t)(b * N_ + base_n + rl) * C_ + out_off + chunk * 8) = vv;
  }
  if (WRITE_HS) {
    float ns0 = norm_s[b * N_ + base_n + n0l];
    float ns1 = norm_s[b * N_ + base_n + n1l];
#pragma unroll
    for (int nt = 0; nt < 8; ++nt) {
      uint2 q0, q1;
      q0.x = f2bf(acc[0][nt][0] * ns0) | (f2bf(acc[0][nt][1] * ns0) << 16);
      q0.y = f2bf(acc[0][nt][2] * ns0) | (f2bf(acc[0][nt][3] * ns0) << 16);
      q1.x = f2bf(acc[1][nt][0] * ns1) | (f2bf(acc[1][nt][1] * ns1) << 16);
      q1.y = f2bf(acc[1][nt][2] * ns1) | (f2bf(acc[1][nt][3] * ns1) << 16);
      *(uint2*)&As[swz(n0l, nt * 16 + fb)] = q0;
      *(uint2*)&As[swz(n1l, nt * 16 + fb)] = q1;
    }
#pragma unroll
    for (int it = 0; it < 8; ++it) {
      int rl = rl0 + it * 4 + rrow;
      uint4 vv = *(const uint4*)&As[swz(rl, chunk * 8)];
      *(uint4*)(hs_out + (size_t)(b * N_ + base_n + rl) * F_ + chunk * 8) = vv;
    }
  }
}

// ---------------- score stage 1: y[n] = (cr[n] . Ws) * norm_s[n] ----------------
__global__ __launch_bounds__(256) void k_score_y(const unsigned short* __restrict__ cr,
                                                 const float* __restrict__ Wsc,
                                                 const float* __restrict__ norm_s,
                                                 float* __restrict__ y) {
  int node = blockIdx.x * 4 + (threadIdx.x >> 6);
  int lane = threadIdx.x & 63;
  const unsigned short* row = cr + (size_t)node * C_;
  float acc = 0.f;
  for (int f = lane; f < C_; f += 64) acc += bf2f(row[f]) * Wsc[f];
  for (int off = 32; off > 0; off >>= 1) acc += __shfl_xor(acc, off);
  if (lane == 0) y[node] = acc * norm_s[node];
}

// ---------------- score stage 2: score[n] = norm_d[n] * sum_in y[src] + bs ----------------
__global__ __launch_bounds__(256) void k_score_agg(const float* __restrict__ y,
                                                   const int* __restrict__ row_ptr,
                                                   const int* __restrict__ csr,
                                                   const float* __restrict__ norm_d,
                                                   const float* __restrict__ bs,
                                                   float* __restrict__ score) {
  int node = blockIdx.x * 256 + threadIdx.x;
  int b = node >> 11, n = node & (N_ - 1);
  int r0 = row_ptr[b * (N_ + 1) + n], r1 = row_ptr[b * (N_ + 1) + n + 1];
  const int* cs = csr + (size_t)b * E_;
  float a = 0.f;
  for (int e = r0; e < r1; ++e) a += y[b * N_ + cs[e]];
  score[node] = norm_d[node] * a + bs[0];
}

// ---------------- top-k selection per graph (K=1024 of 2048) ----------------
__global__ __launch_bounds__(256) void k_topk(const float* __restrict__ score,
                                              float* __restrict__ selw,
                                              int* __restrict__ flags) {
  __shared__ unsigned int keys[N_];
  __shared__ int red[256];
  int b = blockIdx.x, t = threadIdx.x;
  for (int i = t; i < N_; i += 256) {
    unsigned u = __float_as_uint(score[b * N_ + i]);
    keys[i] = (u & 0x80000000u) ? ~u : (u | 0x80000000u);
  }
  __syncthreads();
  unsigned prefix = 0;
  for (int bit = 31; bit >= 0; bit--) {
    unsigned cand = prefix | (1u << bit);
    int c = 0;
    for (int i = t; i < N_; i += 256) c += ((keys[i] >> bit) >= (cand >> bit));
    red[t] = c;
    __syncthreads();
    for (int off = 128; off > 0; off >>= 1) { if (t < off) red[t] += red[t + off]; __syncthreads(); }
    if (red[0] >= K_) prefix = cand;
    __syncthreads();
  }
  unsigned T = prefix;
  int c = 0;
  for (int i = t; i < N_; i += 256) c += (keys[i] > T);
  red[t] = c;
  __syncthreads();
  for (int off = 128; off > 0; off >>= 1) { if (t < off) red[t] += red[t + off]; __syncthreads(); }
  int R = K_ - red[0];                          // ties to take, index order
  __syncthreads();
  unsigned kk[8]; int myt = 0;
  for (int j = 0; j < 8; j++) { kk[j] = keys[t * 8 + j]; myt += (kk[j] == T); }
  red[t] = myt;
  __syncthreads();
  for (int off = 1; off < 256; off <<= 1) {
    int x = (t >= off) ? red[t - off] : 0;
    __syncthreads();
    red[t] += x;
    __syncthreads();
  }
  int rank = red[t] - myt;
  for (int j = 0; j < 8; j++) {
    int i = t * 8 + j;
    bool tie = (kk[j] == T);
    bool sel = (kk[j] > T) || (tie && rank < R);
    if (tie) rank++;
    flags[b * N_ + i] = sel ? 1 : 0;
    selw[b * N_ + i] = sel ? tanhf(score[b * N_ + i]) : 0.f;
  }
}

// ---------------- readout partials: sum & max of selected tanh-weighted rows ----------------
__global__ __launch_bounds__(384) void k_readout_part(const unsigned short* __restrict__ cr,
                                                      const float* __restrict__ selw,
                                                      const int* __restrict__ flags,
                                                      float* __restrict__ psum,
                                                      float* __restrict__ pmax) {
  __shared__ int fl[128];
  __shared__ float wv[128];
  int b = blockIdx.x >> 4, ch = blockIdx.x & 15;
  int f = threadIdx.x;
  int n0 = ch * 128;
  if (f < 128) { fl[f] = flags[b * N_ + n0 + f]; wv[f] = selw[b * N_ + n0 + f]; }
  __syncthreads();
  float sum = 0.f, mx = -3.402823466e38f;
  const unsigned short* base = cr + ((size_t)b * N_ + n0) * C_ + f;
  for (int n = 0; n < 128; n++) {
    float v = bf2f(base[(size_t)n * C_]);
    if (fl[n]) { float x = v * wv[n]; sum += x; mx = fmaxf(mx, x); }
  }
  psum[((size_t)b * 16 + ch) * C_ + f] = sum;
  pmax[((size_t)b * 16 + ch) * C_ + f] = mx;
}

__global__ __launch_bounds__(384) void k_readout_red(const float* __restrict__ psum,
                                                     const float* __restrict__ pmax,
                                                     float* __restrict__ g) {
  int b = blockIdx.x, f = threadIdx.x;
  float s = 0.f, m = -3.402823466e38f;
  for (int ch = 0; ch < 16; ch++) {
    s += psum[((size_t)b * 16 + ch) * C_ + f];
    m = fmaxf(m, pmax[((size_t)b * 16 + ch) * C_ + f]);
  }
  g[b * 768 + f] = s * (1.f / K_);
  g[b * 768 + C_ + f] = m;
}

// ---------------- MLP layer 1: h1 = g @ w1 ----------------
__global__ __launch_bounds__(128) void k_mlp1(const float* __restrict__ g,
                                              const float* __restrict__ w1,
                                              float* __restrict__ h1) {
  __shared__ float gr[768];
  int b = blockIdx.x, t = threadIdx.x;
  for (int i = t; i < 768; i += 128) gr[i] = g[b * 768 + i];
  __syncthreads();
  float acc = 0.f;
  for (int k = 0; k < 768; k++) acc += gr[k] * w1[(size_t)k * 128 + t];
  h1[b * 128 + t] = acc;
}

// ---------------- BN + ReLU + mlp_w2 + log_softmax ----------------
__global__ __launch_bounds__(128) void k_mlp2(const float* __restrict__ h1,
                                              const float* __restrict__ bn_g,
                                              const float* __restrict__ bn_b,
                                              const float* __restrict__ w2,
                                              float* __restrict__ out) {
  __shared__ float hn[64][128];
  __shared__ float o[64][10];
  int t = threadIdx.x;   // 128
  float mean = 0.f;
  for (int r = 0; r < 64; r++) mean += h1[r * 128 + t];
  mean *= (1.f / 64.f);
  float var = 0.f;
  for (int r = 0; r < 64; r++) { float d = h1[r * 128 + t] - mean; var += d * d; }
  var *= (1.f / 64.f);
  float sc = bn_g[t] * rsqrtf(var + 1e-5f), sh = bn_b[t];
  for (int r = 0; r < 64; r++) {
    float v = (h1[r * 128 + t] - mean) * sc + sh;
    hn[r][t] = fmaxf(v, 0.f);
  }
  __syncthreads();
  for (int j = 0; j < 5; j++) {
    int idx = t + j * 128;           // 0..639
    int r = idx / 10, c = idx % 10;
    float a = 0.f;
    for (int k = 0; k < 128; k++) a += hn[r][k] * w2[k * 10 + c];
    o[r][c] = a;
  }
  __syncthreads();
  if (t < 64) {
    float mx = -3.402823466e38f;
    for (int c = 0; c < 10; c++) mx = fmaxf(mx, o[t][c]);
    float se = 0.f;
    for (int c = 0; c < 10; c++) se += expf(o[t][c] - mx);
    float l = logf(se);
    for (int c = 0; c < 10; c++) out[t * 10 + c] = o[t][c] - mx - l;
  }
}

extern "C" void kernel_launch(void* const* d_in, const int* in_sizes, int n_in,
                              void* d_out, int out_size, void* d_ws, size_t ws_size,
                              hipStream_t stream) {
  const float* feat = (const float*)d_in[0];
  const int* src = (const int*)d_in[1];
  const int* dst = (const int*)d_in[2];
  const float* W0 = (const float*)d_in[3];  const float* b0 = (const float*)d_in[4];
  const float* W1 = (const float*)d_in[5];  const float* b1 = (const float*)d_in[6];
  const float* W2 = (const float*)d_in[7];  const float* b2 = (const float*)d_in[8];
  const float* Ws = (const float*)d_in[9];  const float* bs = (const float*)d_in[10];
  const float* mw1 = (const float*)d_in[11];
  const float* bng = (const float*)d_in[12];
  const float* bnb = (const float*)d_in[13];
  const float* mw2 = (const float*)d_in[14];
  float* out = (float*)d_out;

  char* p = (char*)d_ws;
  auto alloc = [&](size_t bytes) -> void* {
    void* r = (void*)p;
    p += (bytes + 255) & ~(size_t)255;
    return r;
  };
  int* row_ptr = (int*)alloc((size_t)B_ * (N_ + 1) * 4);
  float* norm_s = (float*)alloc((size_t)NB_ * 4);
  float* norm_d = (float*)alloc((size_t)NB_ * 4);
  int* csr      = (int*)alloc((size_t)B_ * E_ * 4);
  unsigned short* cr  = (unsigned short*)alloc((size_t)NB_ * C_ * 2);
  unsigned short* hs0 = (unsigned short*)alloc((size_t)NB_ * F_ * 2);   // ping
  unsigned short* hs1 = (unsigned short*)alloc((size_t)NB_ * F_ * 2);   // pong
  float* y     = (float*)alloc((size_t)NB_ * 4);
  float* score = (float*)alloc((size_t)NB_ * 4);
  float* selw  = (float*)alloc((size_t)NB_ * 4);
  int* flags   = (int*)alloc((size_t)NB_ * 4);
  float* psum  = (float*)alloc((size_t)B_ * 16 * C_ * 4);
  float* pmax  = (float*)alloc((size_t)B_ * 16 * C_ * 4);
  float* g     = (float*)alloc((size_t)B_ * 768 * 4);
  float* h1    = (float*)alloc((size_t)B_ * 128 * 4);
  unsigned short* wp0h = (unsigned short*)alloc(16384 * 2);
  unsigned short* wp0l = (unsigned short*)alloc(16384 * 2);
  unsigned short* wp1h = (unsigned short*)alloc(16384 * 2);
  unsigned short* wp1l = (unsigned short*)alloc(16384 * 2);
  unsigned short* wp2h = (unsigned short*)alloc(16384 * 2);
  unsigned short* wp2l = (unsigned short*)alloc(16384 * 2);

  // prep: 4 blocks per graph, range-partitioned, no global atomics
  k_prep<<<dim3(B_ * 4), dim3(1024), 0, stream>>>(src, dst, norm_s, norm_d, row_ptr, csr);

  // weight packs: 32 frags * 64 lanes = 2048 threads = 8 blocks
  k_packW<<<dim3(8), dim3(256), 0, stream>>>(W0, wp0h, wp0l);
  k_packW<<<dim3(8), dim3(256), 0, stream>>>(W1, wp1h, wp1l);
  k_packW<<<dim3(8), dim3(256), 0, stream>>>(W2, wp2h, wp2l);

  // hs0 = feat * norm_s (bf16), XCD-pinned
  k_f2bf_scaled<<<dim3(NB_ / 16), dim3(256), 0, stream>>>(feat, norm_s, hs0);

  // fused layers (hs ping-pong: in-kernel readers and writers must use different buffers)
  k_layer<true><<<dim3(NB_ / 128), dim3(256), 0, stream>>>(hs0, row_ptr, csr, norm_d,
                                                           wp0h, wp0l, b0, cr, 0, norm_s, hs1);
  k_layer<true><<<dim3(NB_ / 128), dim3(256), 0, stream>>>(hs1, row_ptr, csr, norm_d,
                                                           wp1h, wp1l, b1, cr, 128, norm_s, hs0);
  k_layer<false><<<dim3(NB_ / 128), dim3(256), 0, stream>>>(hs0, row_ptr, csr, norm_d,
                                                            wp2h, wp2l, b2, cr, 256, norm_s, nullptr);

  // SAGPool score
  k_score_y<<<dim3(NB_ / 4), dim3(256), 0, stream>>>(cr, Ws, norm_s, y);
  k_score_agg<<<dim3(NB_ / 256), dim3(256), 0, stream>>>(y, row_ptr, csr, norm_d, bs, score);
  k_topk<<<dim3(B_), dim3(256), 0, stream>>>(score, selw, flags);

  // readout
  k_readout_part<<<dim3(B_ * 16), dim3(384), 0, stream>>>(cr, selw, flags, psum, pmax);
  k_readout_red<<<dim3(B_), dim3(384), 0, stream>>>(psum, pmax, g);

  // MLP
  k_mlp1<<<dim3(B_), dim3(128), 0, stream>>>(g, mw1, h1);
  k_mlp2<<<dim3(1), dim3(128), 0, stream>>>(h1, bng, bnb, mw2, out);
}

// Round 13
// 373.978 us; speedup vs baseline: 1.5074x; 1.3360x over previous
//
#include <hip/hip_runtime.h>
#include <hip/hip_bf16.h>
#include <math.h>

#define B_   64
#define N_   2048
#define E_   32768
#define K_   1024
#define F_   128
#define C_   384
#define NB_  (B_ * N_)

typedef __bf16 bf16x8 __attribute__((ext_vector_type(8)));
typedef float  f32x4  __attribute__((ext_vector_type(4)));

__device__ __forceinline__ float bf2f(unsigned int u) {
  return __uint_as_float(u << 16);   // uses low 16 bits
}
__device__ __forceinline__ unsigned int f2bf(float f) {
  unsigned int x = __float_as_uint(f);
  return (x + 0x7fffu + ((x >> 16) & 1u)) >> 16;   // RNE
}
// LDS staging index: row-major [128][128] shorts, XOR swizzle at 8-short granules.
__device__ __forceinline__ int swz(int row, int scol) {
  return (row * F_ + scol) ^ ((row & 7) << 3);
}

// ---------------- graph prep: 4 blocks per graph, each owns a 512-node range ----------------
__global__ __launch_bounds__(1024) void k_prep(const int* __restrict__ src,
                                               const int* __restrict__ dst,
                                               float* __restrict__ norm_s,
                                               float* __restrict__ norm_d,
                                               int* __restrict__ row_ptr,
                                               int* __restrict__ csr) {
  __shared__ int h_in[512];
  __shared__ int h_out[512];
  __shared__ int rowst[512];
  __shared__ int part[512];
  __shared__ int rtot[4];
  int b = blockIdx.x >> 2, r = blockIdx.x & 3;
  int lo = r << 9;
  int t = threadIdx.x;
  if (t < 512) { h_in[t] = 0; h_out[t] = 0; }
  if (t < 4) rtot[t] = 0;
  __syncthreads();
  const int* sp = src + (size_t)b * E_;
  const int* dp = dst + (size_t)b * E_;
  int c0 = 0, c1 = 0, c2 = 0, c3 = 0;
  for (int e0 = t; e0 < E_; e0 += 4096) {
    int s0 = sp[e0],        d0 = dp[e0];
    int s1 = sp[e0 + 1024], d1 = dp[e0 + 1024];
    int s2 = sp[e0 + 2048], d2 = dp[e0 + 2048];
    int s3 = sp[e0 + 3072], d3 = dp[e0 + 3072];
    int dr0 = d0 >> 9, dr1 = d1 >> 9, dr2 = d2 >> 9, dr3 = d3 >> 9;
    c0 += (dr0 == 0) + (dr1 == 0) + (dr2 == 0) + (dr3 == 0);
    c1 += (dr0 == 1) + (dr1 == 1) + (dr2 == 1) + (dr3 == 1);
    c2 += (dr0 == 2) + (dr1 == 2) + (dr2 == 2) + (dr3 == 2);
    c3 += (dr0 == 3) + (dr1 == 3) + (dr2 == 3) + (dr3 == 3);
    if (dr0 == r) atomicAdd(&h_in[d0 - lo], 1);
    if (dr1 == r) atomicAdd(&h_in[d1 - lo], 1);
    if (dr2 == r) atomicAdd(&h_in[d2 - lo], 1);
    if (dr3 == r) atomicAdd(&h_in[d3 - lo], 1);
    if ((s0 >> 9) == r) atomicAdd(&h_out[s0 - lo], 1);
    if ((s1 >> 9) == r) atomicAdd(&h_out[s1 - lo], 1);
    if ((s2 >> 9) == r) atomicAdd(&h_out[s2 - lo], 1);
    if ((s3 >> 9) == r) atomicAdd(&h_out[s3 - lo], 1);
  }
  if (c0) atomicAdd(&rtot[0], c0);
  if (c1) atomicAdd(&rtot[1], c1);
  if (c2) atomicAdd(&rtot[2], c2);
  if (c3) atomicAdd(&rtot[3], c3);
  __syncthreads();
  if (t < 512) {
    int dv = h_out[t], di = h_in[t];
    norm_s[b * N_ + lo + t] = dv > 0 ? rsqrtf((float)dv) : 0.f;
    norm_d[b * N_ + lo + t] = di > 0 ? rsqrtf((float)di) : 0.f;
  }
  int base = 0;
  if (r > 0) base += rtot[0];
  if (r > 1) base += rtot[1];
  if (r > 2) base += rtot[2];
  if (t < 512) part[t] = h_in[t];
  __syncthreads();
  for (int off = 1; off < 512; off <<= 1) {
    int x = (t >= off && t < 512) ? part[t - off] : 0;
    __syncthreads();
    if (t < 512) part[t] += x;
    __syncthreads();
  }
  if (t < 512) {
    int st = base + part[t] - h_in[t];
    rowst[t] = st;
    row_ptr[b * (N_ + 1) + lo + t] = st;
    h_in[t] = 0;
  }
  if (r == 3 && t == 511) row_ptr[b * (N_ + 1) + N_] = base + part[511];
  __syncthreads();
  int* cg = csr + (size_t)b * E_;
  for (int e0 = t; e0 < E_; e0 += 4096) {
    int d0 = dp[e0],        s0 = sp[e0];
    int d1 = dp[e0 + 1024], s1 = sp[e0 + 1024];
    int d2 = dp[e0 + 2048], s2 = sp[e0 + 2048];
    int d3 = dp[e0 + 3072], s3 = sp[e0 + 3072];
    if ((d0 >> 9) == r) { int pos = rowst[d0 - lo] + atomicAdd(&h_in[d0 - lo], 1); cg[pos] = s0; }
    if ((d1 >> 9) == r) { int pos = rowst[d1 - lo] + atomicAdd(&h_in[d1 - lo], 1); cg[pos] = s1; }
    if ((d2 >> 9) == r) { int pos = rowst[d2 - lo] + atomicAdd(&h_in[d2 - lo], 1); cg[pos] = s2; }
    if ((d3 >> 9) == r) { int pos = rowst[d3 - lo] + atomicAdd(&h_in[d3 - lo], 1); cg[pos] = s3; }
  }
}

// ---------------- feat f32 -> bf16 pre-scaled by norm_s (XCD-pinned per graph) ----------------
__global__ __launch_bounds__(256) void k_f2bf_scaled(const float* __restrict__ in,
                                                     const float* __restrict__ norm_s,
                                                     unsigned short* __restrict__ out) {
  int blk = blockIdx.x;
  int b = ((blk >> 10) << 3) | (blk & 7);
  int nb = (blk >> 3) & 127;
  int t = threadIdx.x;
  int node = b * N_ + nb * 16 + (t >> 4);
  int f0 = (t & 15) * 8;
  float ns = norm_s[node];
  const float4* p = (const float4*)(in + (size_t)node * F_ + f0);
  float4 v0 = p[0], v1 = p[1];
  uint4 o;
  o.x = f2bf(v0.x * ns) | (f2bf(v0.y * ns) << 16);
  o.y = f2bf(v0.z * ns) | (f2bf(v0.w * ns) << 16);
  o.z = f2bf(v1.x * ns) | (f2bf(v1.y * ns) << 16);
  o.w = f2bf(v1.z * ns) | (f2bf(v1.w * ns) << 16);
  *(uint4*)(out + (size_t)node * F_ + f0) = o;
}

// ---------------- aggregate (R9 shape): 16 lanes/node, 16 nodes/block, 8-deep gathers ----------------
__global__ __launch_bounds__(256) void k_agg(const unsigned short* __restrict__ hs,
                                             const int* __restrict__ row_ptr,
                                             const int* __restrict__ csr,
                                             const float* __restrict__ norm_d,
                                             unsigned short* __restrict__ agg) {
  int blk = blockIdx.x;
  int b = ((blk >> 10) << 3) | (blk & 7);
  int nb = (blk >> 3) & 127;
  int t = threadIdx.x;
  int nl = t >> 4, f8 = t & 15;
  int n = nb * 16 + nl;
  int node = b * N_ + n;
  int r0 = row_ptr[b * (N_ + 1) + n], r1 = row_ptr[b * (N_ + 1) + n + 1];
  const int* cs = csr + (size_t)b * E_;
  const unsigned short* hb = hs + ((size_t)b * N_) * F_ + f8 * 8;
  float a0 = 0.f, a1 = 0.f, a2 = 0.f, a3 = 0.f, a4 = 0.f, a5 = 0.f, a6 = 0.f, a7 = 0.f;
#define ACC8(u) { a0 += bf2f(u.x); a1 += bf2f(u.x >> 16); a2 += bf2f(u.y); a3 += bf2f(u.y >> 16); \
                  a4 += bf2f(u.z); a5 += bf2f(u.z >> 16); a6 += bf2f(u.w); a7 += bf2f(u.w >> 16); }
  int e = r0;
  for (; e + 8 <= r1; e += 8) {
    int s0 = cs[e],     s1 = cs[e + 1], s2 = cs[e + 2], s3 = cs[e + 3];
    int s4 = cs[e + 4], s5 = cs[e + 5], s6 = cs[e + 6], s7 = cs[e + 7];
    uint4 u0 = *(const uint4*)(hb + (size_t)s0 * F_);
    uint4 u1 = *(const uint4*)(hb + (size_t)s1 * F_);
    uint4 u2 = *(const uint4*)(hb + (size_t)s2 * F_);
    uint4 u3 = *(const uint4*)(hb + (size_t)s3 * F_);
    uint4 u4 = *(const uint4*)(hb + (size_t)s4 * F_);
    uint4 u5 = *(const uint4*)(hb + (size_t)s5 * F_);
    uint4 u6 = *(const uint4*)(hb + (size_t)s6 * F_);
    uint4 u7 = *(const uint4*)(hb + (size_t)s7 * F_);
    ACC8(u0); ACC8(u1); ACC8(u2); ACC8(u3);
    ACC8(u4); ACC8(u5); ACC8(u6); ACC8(u7);
  }
  for (; e < r1; ++e) {
    int s0 = cs[e];
    uint4 u0 = *(const uint4*)(hb + (size_t)s0 * F_);
    ACC8(u0);
  }
#undef ACC8
  float wd = norm_d[node];
  uint4 o;
  o.x = f2bf(a0 * wd) | (f2bf(a1 * wd) << 16);
  o.y = f2bf(a2 * wd) | (f2bf(a3 * wd) << 16);
  o.z = f2bf(a4 * wd) | (f2bf(a5 * wd) << 16);
  o.w = f2bf(a6 * wd) | (f2bf(a7 * wd) << 16);
  *(uint4*)(agg + (size_t)node * F_ + f8 * 8) = o;
}

// ---------------- pack W (f32 [128k][128n]) into MFMA fragment layout, bf16 hi/lo ----------------
__global__ __launch_bounds__(256) void k_packW(const float* __restrict__ W,
                                               unsigned short* __restrict__ wp_hi,
                                               unsigned short* __restrict__ wp_lo) {
  int tid = blockIdx.x * 256 + threadIdx.x;
  int lane = tid & 63, frag = tid >> 6;
  if (frag >= 32) return;
  int kt = frag >> 3, nt = frag & 7;
  int k0 = kt * 32 + (lane >> 4) * 8;
  int n = nt * 16 + (lane & 15);
  for (int j = 0; j < 8; j++) {
    float w = W[(size_t)(k0 + j) * 128 + n];
    unsigned int hi = f2bf(w);
    float whi = bf2f(hi);
    unsigned int lo = f2bf(w - whi);
    wp_hi[(size_t)tid * 8 + j] = (unsigned short)hi;
    wp_lo[(size_t)tid * 8 + j] = (unsigned short)lo;
  }
}

// ---------------- MFMA GEMM (transposed) + LDS-staged coalesced epilogue + fused score-y ----------------
// XCD-pinned: blockIdx = (b>>3)*128 + nb*8 + (b&7), nb in [0,16). 32 nodes/wave.
// ymode: 0 = y[node]  = partial   (layer 0)
//        1 = y[node] += partial   (layer 1)
//        2 = y[node]  = (y[node]+partial)*norm_s[node]  (layer 2, finalize)
template <bool WRITE_HS>
__global__ __launch_bounds__(256) void k_gemm_mfma(const unsigned short* __restrict__ agg,
                                                   const unsigned short* __restrict__ wp_hi,
                                                   const unsigned short* __restrict__ wp_lo,
                                                   const float* __restrict__ bias,
                                                   unsigned short* __restrict__ cr,
                                                   int out_off,
                                                   const float* __restrict__ norm_s,
                                                   unsigned short* __restrict__ hs,
                                                   const float* __restrict__ Wsc,
                                                   float* __restrict__ ybuf,
                                                   int ymode) {
  __shared__ unsigned short Stg[128 * F_];       // 32 KB staging
  int blk = blockIdx.x;
  int b = ((blk >> 7) << 3) | (blk & 7);
  int nb = (blk >> 3) & 15;
  int t = threadIdx.x;
  int wave = t >> 6, lane = t & 63;
  int gbase = b * N_ + nb * 128;                 // global node base of block
  int rl0 = wave * 32;                           // local row base of wave
  int arow = lane & 15, kg = lane >> 4;

  f32x4 acc[2][8];
#pragma unroll
  for (int i = 0; i < 2; i++)
#pragma unroll
    for (int j = 0; j < 8; j++) acc[i][j] = (f32x4){0.f, 0.f, 0.f, 0.f};

#pragma unroll
  for (int kt = 0; kt < 4; ++kt) {
    bf16x8 a0 = *(const bf16x8*)(agg + (size_t)(gbase + rl0 + arow) * F_ + kt * 32 + kg * 8);
    bf16x8 a1 = *(const bf16x8*)(agg + (size_t)(gbase + rl0 + 16 + arow) * F_ + kt * 32 + kg * 8);
    const unsigned short* bh = wp_hi + ((size_t)(kt * 8) * 64 + lane) * 8;
    const unsigned short* bl = wp_lo + ((size_t)(kt * 8) * 64 + lane) * 8;
#pragma unroll
    for (int nt = 0; nt < 8; ++nt) {
      bf16x8 bhv = *(const bf16x8*)(bh + (size_t)nt * 64 * 8);
      bf16x8 blv = *(const bf16x8*)(bl + (size_t)nt * 64 * 8);
      acc[0][nt] = __builtin_amdgcn_mfma_f32_16x16x32_bf16(bhv, a0, acc[0][nt], 0, 0, 0);
      acc[0][nt] = __builtin_amdgcn_mfma_f32_16x16x32_bf16(blv, a0, acc[0][nt], 0, 0, 0);
      acc[1][nt] = __builtin_amdgcn_mfma_f32_16x16x32_bf16(bhv, a1, acc[1][nt], 0, 0, 0);
      acc[1][nt] = __builtin_amdgcn_mfma_f32_16x16x32_bf16(blv, a1, acc[1][nt], 0, 0, 0);
    }
  }

  // fold bias, pack bf16, stage to own wave region, accumulate score-y partials
  int fb = kg * 4;
  int l0 = rl0 + arow, l1 = rl0 + 16 + arow;     // local rows this lane owns
  float yp0 = 0.f, yp1 = 0.f;
#pragma unroll
  for (int nt = 0; nt < 8; ++nt) {
    float4 bv = *(const float4*)(bias + nt * 16 + fb);
    acc[0][nt][0] += bv.x; acc[0][nt][1] += bv.y; acc[0][nt][2] += bv.z; acc[0][nt][3] += bv.w;
    acc[1][nt][0] += bv.x; acc[1][nt][1] += bv.y; acc[1][nt][2] += bv.z; acc[1][nt][3] += bv.w;
    uint2 p0, p1;
    p0.x = f2bf(acc[0][nt][0]) | (f2bf(acc[0][nt][1]) << 16);
    p0.y = f2bf(acc[0][nt][2]) | (f2bf(acc[0][nt][3]) << 16);
    p1.x = f2bf(acc[1][nt][0]) | (f2bf(acc[1][nt][1]) << 16);
    p1.y = f2bf(acc[1][nt][2]) | (f2bf(acc[1][nt][3]) << 16);
    *(uint2*)&Stg[swz(l0, nt * 16 + fb)] = p0;
    *(uint2*)&Stg[swz(l1, nt * 16 + fb)] = p1;
    float4 wv = *(const float4*)(Wsc + out_off + nt * 16 + fb);
    yp0 += bf2f(p0.x) * wv.x + bf2f(p0.x >> 16) * wv.y + bf2f(p0.y) * wv.z + bf2f(p0.y >> 16) * wv.w;
    yp1 += bf2f(p1.x) * wv.x + bf2f(p1.x >> 16) * wv.y + bf2f(p1.y) * wv.z + bf2f(p1.y >> 16) * wv.w;
  }
  // reduce chunk-dot across the 4 kg groups (lanes arow, arow+16, arow+32, arow+48)
  yp0 += __shfl_xor(yp0, 16); yp0 += __shfl_xor(yp0, 32);
  yp1 += __shfl_xor(yp1, 16); yp1 += __shfl_xor(yp1, 32);
  if (kg == 0) {
    int n0 = gbase + l0, n1 = gbase + l1;
    if (ymode == 0)      { ybuf[n0] = yp0; ybuf[n1] = yp1; }
    else if (ymode == 1) { ybuf[n0] += yp0; ybuf[n1] += yp1; }
    else                 { ybuf[n0] = (ybuf[n0] + yp0) * norm_s[n0];
                           ybuf[n1] = (ybuf[n1] + yp1) * norm_s[n1]; }
  }

  // coalesced cr store: own 32 rows, 4 rows x 16 chunks per iteration (256B/row)
  int rrow = lane >> 4, chunk = lane & 15;
#pragma unroll
  for (int it = 0; it < 8; ++it) {
    int rl = rl0 + it * 4 + rrow;
    uint4 vv = *(const uint4*)&Stg[swz(rl, chunk * 8)];
    *(uint4*)(cr + (size_t)(gbase + rl) * C_ + out_off + chunk * 8) = vv;
  }
  if (WRITE_HS) {
    float ns0 = norm_s[gbase + l0];
    float ns1 = norm_s[gbase + l1];
#pragma unroll
    for (int nt = 0; nt < 8; ++nt) {
      uint2 q0, q1;
      q0.x = f2bf(acc[0][nt][0] * ns0) | (f2bf(acc[0][nt][1] * ns0) << 16);
      q0.y = f2bf(acc[0][nt][2] * ns0) | (f2bf(acc[0][nt][3] * ns0) << 16);
      q1.x = f2bf(acc[1][nt][0] * ns1) | (f2bf(acc[1][nt][1] * ns1) << 16);
      q1.y = f2bf(acc[1][nt][2] * ns1) | (f2bf(acc[1][nt][3] * ns1) << 16);
      *(uint2*)&Stg[swz(l0, nt * 16 + fb)] = q0;
      *(uint2*)&Stg[swz(l1, nt * 16 + fb)] = q1;
    }
#pragma unroll
    for (int it = 0; it < 8; ++it) {
      int rl = rl0 + it * 4 + rrow;
      uint4 vv = *(const uint4*)&Stg[swz(rl, chunk * 8)];
      *(uint4*)(hs + (size_t)(gbase + rl) * F_ + chunk * 8) = vv;
    }
  }
}

// ---------------- score stage 2: score[n] = norm_d[n] * sum_in y[src] + bs ----------------
__global__ __launch_bounds__(256) void k_score_agg(const float* __restrict__ y,
                                                   const int* __restrict__ row_ptr,
                                                   const int* __restrict__ csr,
                                                   const float* __restrict__ norm_d,
                                                   const float* __restrict__ bs,
                                                   float* __restrict__ score) {
  int node = blockIdx.x * 256 + threadIdx.x;
  int b = node >> 11, n = node & (N_ - 1);
  int r0 = row_ptr[b * (N_ + 1) + n], r1 = row_ptr[b * (N_ + 1) + n + 1];
  const int* cs = csr + (size_t)b * E_;
  float a = 0.f;
  for (int e = r0; e < r1; ++e) a += y[b * N_ + cs[e]];
  score[node] = norm_d[node] * a + bs[0];
}

// ---------------- top-k selection per graph; emits compacted indices + tanh weights ----------------
__global__ __launch_bounds__(256) void k_topk(const float* __restrict__ score,
                                              int* __restrict__ idxs,
                                              float* __restrict__ wsel) {
  __shared__ unsigned int keys[N_];
  __shared__ int red[256];
  int b = blockIdx.x, t = threadIdx.x;
  for (int i = t; i < N_; i += 256) {
    unsigned u = __float_as_uint(score[b * N_ + i]);
    keys[i] = (u & 0x80000000u) ? ~u : (u | 0x80000000u);
  }
  __syncthreads();
  unsigned prefix = 0;
  for (int bit = 31; bit >= 0; bit--) {
    unsigned cand = prefix | (1u << bit);
    int c = 0;
    for (int i = t; i < N_; i += 256) c += ((keys[i] >> bit) >= (cand >> bit));
    red[t] = c;
    __syncthreads();
    for (int off = 128; off > 0; off >>= 1) { if (t < off) red[t] += red[t + off]; __syncthreads(); }
    if (red[0] >= K_) prefix = cand;
    __syncthreads();
  }
  unsigned T = prefix;
  int c = 0;
  for (int i = t; i < N_; i += 256) c += (keys[i] > T);
  red[t] = c;
  __syncthreads();
  for (int off = 128; off > 0; off >>= 1) { if (t < off) red[t] += red[t + off]; __syncthreads(); }
  int R = K_ - red[0];                          // ties to take, index order
  __syncthreads();
  unsigned kk[8]; int myt = 0;
  for (int j = 0; j < 8; j++) { kk[j] = keys[t * 8 + j]; myt += (kk[j] == T); }
  red[t] = myt;
  __syncthreads();
  for (int off = 1; off < 256; off <<= 1) {
    int x = (t >= off) ? red[t - off] : 0;
    __syncthreads();
    red[t] += x;
    __syncthreads();
  }
  int rank = red[t] - myt;
  bool sb[8]; int csel = 0;
  for (int j = 0; j < 8; j++) {
    bool tie = (kk[j] == T);
    bool sel = (kk[j] > T) || (tie && rank < R);
    if (tie) rank++;
    sb[j] = sel; csel += sel;
  }
  __syncthreads();
  // scan sel counts -> compact positions
  red[t] = csel;
  __syncthreads();
  for (int off = 1; off < 256; off <<= 1) {
    int x = (t >= off) ? red[t - off] : 0;
    __syncthreads();
    red[t] += x;
    __syncthreads();
  }
  int pos = red[t] - csel;
  for (int j = 0; j < 8; j++) {
    if (sb[j]) {
      int i = t * 8 + j;
      idxs[b * K_ + pos] = i;
      wsel[b * K_ + pos] = tanhf(score[b * N_ + i]);
      pos++;
    }
  }
}

// ---------------- readout partials over SELECTED rows only ----------------
__global__ __launch_bounds__(384) void k_readout_part(const unsigned short* __restrict__ cr,
                                                      const float* __restrict__ wsel,
                                                      const int* __restrict__ idxs,
                                                      float* __restrict__ psum,
                                                      float* __restrict__ pmax) {
  __shared__ int rows[64];
  __shared__ float wv[64];
  int b = blockIdx.x >> 4, ch = blockIdx.x & 15;
  int f = threadIdx.x;
  if (f < 64) {
    rows[f] = idxs[b * K_ + ch * 64 + f];
    wv[f] = wsel[b * K_ + ch * 64 + f];
  }
  __syncthreads();
  float sum = 0.f, mx = -3.402823466e38f;
  for (int s = 0; s < 64; s++) {
    float v = bf2f(cr[((size_t)(b * N_ + rows[s])) * C_ + f]);
    float x = v * wv[s];
    sum += x; mx = fmaxf(mx, x);
  }
  psum[((size_t)b * 16 + ch) * C_ + f] = sum;
  pmax[((size_t)b * 16 + ch) * C_ + f] = mx;
}

__global__ __launch_bounds__(384) void k_readout_red(const float* __restrict__ psum,
                                                     const float* __restrict__ pmax,
                                                     float* __restrict__ g) {
  int b = blockIdx.x, f = threadIdx.x;
  float s = 0.f, m = -3.402823466e38f;
  for (int ch = 0; ch < 16; ch++) {
    s += psum[((size_t)b * 16 + ch) * C_ + f];
    m = fmaxf(m, pmax[((size_t)b * 16 + ch) * C_ + f]);
  }
  g[b * 768 + f] = s * (1.f / K_);
  g[b * 768 + C_ + f] = m;
}

// ---------------- MLP layer 1: h1 = g @ w1 ----------------
__global__ __launch_bounds__(128) void k_mlp1(const float* __restrict__ g,
                                              const float* __restrict__ w1,
                                              float* __restrict__ h1) {
  __shared__ float gr[768];
  int b = blockIdx.x, t = threadIdx.x;
  for (int i = t; i < 768; i += 128) gr[i] = g[b * 768 + i];
  __syncthreads();
  float acc = 0.f;
  for (int k = 0; k < 768; k++) acc += gr[k] * w1[(size_t)k * 128 + t];
  h1[b * 128 + t] = acc;
}

// ---------------- BN + ReLU + mlp_w2 + log_softmax ----------------
__global__ __launch_bounds__(128) void k_mlp2(const float* __restrict__ h1,
                                              const float* __restrict__ bn_g,
                                              const float* __restrict__ bn_b,
                                              const float* __restrict__ w2,
                                              float* __restrict__ out) {
  __shared__ float hn[64][128];
  __shared__ float o[64][10];
  int t = threadIdx.x;   // 128
  float mean = 0.f;
  for (int r = 0; r < 64; r++) mean += h1[r * 128 + t];
  mean *= (1.f / 64.f);
  float var = 0.f;
  for (int r = 0; r < 64; r++) { float d = h1[r * 128 + t] - mean; var += d * d; }
  var *= (1.f / 64.f);
  float sc = bn_g[t] * rsqrtf(var + 1e-5f), sh = bn_b[t];
  for (int r = 0; r < 64; r++) {
    float v = (h1[r * 128 + t] - mean) * sc + sh;
    hn[r][t] = fmaxf(v, 0.f);
  }
  __syncthreads();
  for (int j = 0; j < 5; j++) {
    int idx = t + j * 128;           // 0..639
    int r = idx / 10, c = idx % 10;
    float a = 0.f;
    for (int k = 0; k < 128; k++) a += hn[r][k] * w2[k * 10 + c];
    o[r][c] = a;
  }
  __syncthreads();
  if (t < 64) {
    float mx = -3.402823466e38f;
    for (int c = 0; c < 10; c++) mx = fmaxf(mx, o[t][c]);
    float se = 0.f;
    for (int c = 0; c < 10; c++) se += expf(o[t][c] - mx);
    float l = logf(se);
    for (int c = 0; c < 10; c++) out[t * 10 + c] = o[t][c] - mx - l;
  }
}

extern "C" void kernel_launch(void* const* d_in, const int* in_sizes, int n_in,
                              void* d_out, int out_size, void* d_ws, size_t ws_size,
                              hipStream_t stream) {
  const float* feat = (const float*)d_in[0];
  const int* src = (const int*)d_in[1];
  const int* dst = (const int*)d_in[2];
  const float* W0 = (const float*)d_in[3];  const float* b0 = (const float*)d_in[4];
  const float* W1 = (const float*)d_in[5];  const float* b1 = (const float*)d_in[6];
  const float* W2 = (const float*)d_in[7];  const float* b2 = (const float*)d_in[8];
  const float* Ws = (const float*)d_in[9];  const float* bs = (const float*)d_in[10];
  const float* mw1 = (const float*)d_in[11];
  const float* bng = (const float*)d_in[12];
  const float* bnb = (const float*)d_in[13];
  const float* mw2 = (const float*)d_in[14];
  float* out = (float*)d_out;

  char* p = (char*)d_ws;
  auto alloc = [&](size_t bytes) -> void* {
    void* r = (void*)p;
    p += (bytes + 255) & ~(size_t)255;
    return r;
  };
  int* row_ptr = (int*)alloc((size_t)B_ * (N_ + 1) * 4);
  float* norm_s = (float*)alloc((size_t)NB_ * 4);
  float* norm_d = (float*)alloc((size_t)NB_ * 4);
  int* csr      = (int*)alloc((size_t)B_ * E_ * 4);
  unsigned short* cr  = (unsigned short*)alloc((size_t)NB_ * C_ * 2);
  unsigned short* agg = (unsigned short*)alloc((size_t)NB_ * F_ * 2);   // A buffer
  unsigned short* hsb = (unsigned short*)alloc((size_t)NB_ * F_ * 2);   // H buffer
  float* y     = (float*)alloc((size_t)NB_ * 4);
  float* score = (float*)alloc((size_t)NB_ * 4);
  int* idxs    = (int*)alloc((size_t)B_ * K_ * 4);
  float* wsel  = (float*)alloc((size_t)B_ * K_ * 4);
  float* psum  = (float*)alloc((size_t)B_ * 16 * C_ * 4);
  float* pmax  = (float*)alloc((size_t)B_ * 16 * C_ * 4);
  float* g     = (float*)alloc((size_t)B_ * 768 * 4);
  float* h1    = (float*)alloc((size_t)B_ * 128 * 4);
  unsigned short* wp0h = (unsigned short*)alloc(16384 * 2);
  unsigned short* wp0l = (unsigned short*)alloc(16384 * 2);
  unsigned short* wp1h = (unsigned short*)alloc(16384 * 2);
  unsigned short* wp1l = (unsigned short*)alloc(16384 * 2);
  unsigned short* wp2h = (unsigned short*)alloc(16384 * 2);
  unsigned short* wp2l = (unsigned short*)alloc(16384 * 2);

  // prep: 4 blocks per graph, range-partitioned, no global atomics
  k_prep<<<dim3(B_ * 4), dim3(1024), 0, stream>>>(src, dst, norm_s, norm_d, row_ptr, csr);

  // weight packs
  k_packW<<<dim3(8), dim3(256), 0, stream>>>(W0, wp0h, wp0l);
  k_packW<<<dim3(8), dim3(256), 0, stream>>>(W1, wp1h, wp1l);
  k_packW<<<dim3(8), dim3(256), 0, stream>>>(W2, wp2h, wp2l);

  // hs0 = feat * norm_s (bf16), XCD-pinned
  k_f2bf_scaled<<<dim3(NB_ / 16), dim3(256), 0, stream>>>(feat, norm_s, hsb);

  // layer 0
  k_agg<<<dim3(NB_ / 16), dim3(256), 0, stream>>>(hsb, row_ptr, csr, norm_d, agg);
  k_gemm_mfma<true><<<dim3(NB_ / 128), dim3(256), 0, stream>>>(agg, wp0h, wp0l, b0, cr, 0,
                                                               norm_s, hsb, Ws, y, 0);
  // layer 1
  k_agg<<<dim3(NB_ / 16), dim3(256), 0, stream>>>(hsb, row_ptr, csr, norm_d, agg);
  k_gemm_mfma<true><<<dim3(NB_ / 128), dim3(256), 0, stream>>>(agg, wp1h, wp1l, b1, cr, 128,
                                                               norm_s, hsb, Ws, y, 1);
  // layer 2 (finalize y)
  k_agg<<<dim3(NB_ / 16), dim3(256), 0, stream>>>(hsb, row_ptr, csr, norm_d, agg);
  k_gemm_mfma<false><<<dim3(NB_ / 128), dim3(256), 0, stream>>>(agg, wp2h, wp2l, b2, cr, 256,
                                                                norm_s, nullptr, Ws, y, 2);

  // SAGPool score aggregation + top-k (compacted)
  k_score_agg<<<dim3(NB_ / 256), dim3(256), 0, stream>>>(y, row_ptr, csr, norm_d, bs, score);
  k_topk<<<dim3(B_), dim3(256), 0, stream>>>(score, idxs, wsel);

  // readout over selected rows
  k_readout_part<<<dim3(B_ * 16), dim3(384), 0, stream>>>(cr, wsel, idxs, psum, pmax);
  k_readout_red<<<dim3(B_), dim3(384), 0, stream>>>(psum, pmax, g);

  // MLP
  k_mlp1<<<dim3(B_), dim3(128), 0, stream>>>(g, mw1, h1);
  k_mlp2<<<dim3(1), dim3(128), 0, stream>>>(h1, bng, bnb, mw2, out);
}

// Round 14
// 357.152 us; speedup vs baseline: 1.5784x; 1.0471x over previous
//
#include <hip/hip_runtime.h>
#include <hip/hip_bf16.h>
#include <math.h>

#define B_   64
#define N_   2048
#define E_   32768
#define K_   1024
#define F_   128
#define C_   384
#define NB_  (B_ * N_)

typedef __bf16 bf16x8 __attribute__((ext_vector_type(8)));
typedef float  f32x4  __attribute__((ext_vector_type(4)));

__device__ __forceinline__ float bf2f(unsigned int u) {
  return __uint_as_float(u << 16);   // uses low 16 bits
}
__device__ __forceinline__ unsigned int f2bf(float f) {
  unsigned int x = __float_as_uint(f);
  return (x + 0x7fffu + ((x >> 16) & 1u)) >> 16;   // RNE
}
// LDS staging index: row-major [128][128] shorts, XOR swizzle at 8-short granules.
__device__ __forceinline__ int swz(int row, int scol) {
  return (row * F_ + scol) ^ ((row & 7) << 3);
}

// ---------------- graph prep: 4 blocks per graph, each owns a 512-node range ----------------
__global__ __launch_bounds__(1024) void k_prep(const int* __restrict__ src,
                                               const int* __restrict__ dst,
                                               float* __restrict__ norm_s,
                                               float* __restrict__ norm_d,
                                               int* __restrict__ row_ptr,
                                               int* __restrict__ csr) {
  __shared__ int h_in[512];
  __shared__ int h_out[512];
  __shared__ int rowst[512];
  __shared__ int part[512];
  __shared__ int rtot[4];
  int b = blockIdx.x >> 2, r = blockIdx.x & 3;
  int lo = r << 9;
  int t = threadIdx.x;
  if (t < 512) { h_in[t] = 0; h_out[t] = 0; }
  if (t < 4) rtot[t] = 0;
  __syncthreads();
  const int* sp = src + (size_t)b * E_;
  const int* dp = dst + (size_t)b * E_;
  int c0 = 0, c1 = 0, c2 = 0, c3 = 0;
  for (int e0 = t; e0 < E_; e0 += 4096) {
    int s0 = sp[e0],        d0 = dp[e0];
    int s1 = sp[e0 + 1024], d1 = dp[e0 + 1024];
    int s2 = sp[e0 + 2048], d2 = dp[e0 + 2048];
    int s3 = sp[e0 + 3072], d3 = dp[e0 + 3072];
    int dr0 = d0 >> 9, dr1 = d1 >> 9, dr2 = d2 >> 9, dr3 = d3 >> 9;
    c0 += (dr0 == 0) + (dr1 == 0) + (dr2 == 0) + (dr3 == 0);
    c1 += (dr0 == 1) + (dr1 == 1) + (dr2 == 1) + (dr3 == 1);
    c2 += (dr0 == 2) + (dr1 == 2) + (dr2 == 2) + (dr3 == 2);
    c3 += (dr0 == 3) + (dr1 == 3) + (dr2 == 3) + (dr3 == 3);
    if (dr0 == r) atomicAdd(&h_in[d0 - lo], 1);
    if (dr1 == r) atomicAdd(&h_in[d1 - lo], 1);
    if (dr2 == r) atomicAdd(&h_in[d2 - lo], 1);
    if (dr3 == r) atomicAdd(&h_in[d3 - lo], 1);
    if ((s0 >> 9) == r) atomicAdd(&h_out[s0 - lo], 1);
    if ((s1 >> 9) == r) atomicAdd(&h_out[s1 - lo], 1);
    if ((s2 >> 9) == r) atomicAdd(&h_out[s2 - lo], 1);
    if ((s3 >> 9) == r) atomicAdd(&h_out[s3 - lo], 1);
  }
  if (c0) atomicAdd(&rtot[0], c0);
  if (c1) atomicAdd(&rtot[1], c1);
  if (c2) atomicAdd(&rtot[2], c2);
  if (c3) atomicAdd(&rtot[3], c3);
  __syncthreads();
  if (t < 512) {
    int dv = h_out[t], di = h_in[t];
    norm_s[b * N_ + lo + t] = dv > 0 ? rsqrtf((float)dv) : 0.f;
    norm_d[b * N_ + lo + t] = di > 0 ? rsqrtf((float)di) : 0.f;
  }
  int base = 0;
  if (r > 0) base += rtot[0];
  if (r > 1) base += rtot[1];
  if (r > 2) base += rtot[2];
  if (t < 512) part[t] = h_in[t];
  __syncthreads();
  for (int off = 1; off < 512; off <<= 1) {
    int x = (t >= off && t < 512) ? part[t - off] : 0;
    __syncthreads();
    if (t < 512) part[t] += x;
    __syncthreads();
  }
  if (t < 512) {
    int st = base + part[t] - h_in[t];
    rowst[t] = st;
    row_ptr[b * (N_ + 1) + lo + t] = st;
    h_in[t] = 0;
  }
  if (r == 3 && t == 511) row_ptr[b * (N_ + 1) + N_] = base + part[511];
  __syncthreads();
  int* cg = csr + (size_t)b * E_;
  for (int e0 = t; e0 < E_; e0 += 4096) {
    int d0 = dp[e0],        s0 = sp[e0];
    int d1 = dp[e0 + 1024], s1 = sp[e0 + 1024];
    int d2 = dp[e0 + 2048], s2 = sp[e0 + 2048];
    int d3 = dp[e0 + 3072], s3 = sp[e0 + 3072];
    if ((d0 >> 9) == r) { int pos = rowst[d0 - lo] + atomicAdd(&h_in[d0 - lo], 1); cg[pos] = s0; }
    if ((d1 >> 9) == r) { int pos = rowst[d1 - lo] + atomicAdd(&h_in[d1 - lo], 1); cg[pos] = s1; }
    if ((d2 >> 9) == r) { int pos = rowst[d2 - lo] + atomicAdd(&h_in[d2 - lo], 1); cg[pos] = s2; }
    if ((d3 >> 9) == r) { int pos = rowst[d3 - lo] + atomicAdd(&h_in[d3 - lo], 1); cg[pos] = s3; }
  }
}

// ---------------- per-graph counting sort of nodes by in-degree (descending) ----------------
// order[b][pos] = node. Processing order only; per-node math unchanged (bitwise identical).
__global__ __launch_bounds__(256) void k_sort(const int* __restrict__ row_ptr,
                                              int* __restrict__ order) {
  __shared__ int hist[64];
  __shared__ int base[64];
  int b = blockIdx.x, t = threadIdx.x;
  if (t < 64) hist[t] = 0;
  __syncthreads();
  int degs[8];
  const int* rp = row_ptr + b * (N_ + 1);
  for (int j = 0; j < 8; j++) {
    int n = t * 8 + j;
    int d = rp[n + 1] - rp[n];
    degs[j] = d;
    int bin = 63 - min(d, 63);
    atomicAdd(&hist[bin], 1);
  }
  __syncthreads();
  if (t == 0) {
    int run = 0;
    for (int i = 0; i < 64; i++) { base[i] = run; run += hist[i]; hist[i] = 0; }
  }
  __syncthreads();
  for (int j = 0; j < 8; j++) {
    int n = t * 8 + j;
    int bin = 63 - min(degs[j], 63);
    int pos = base[bin] + atomicAdd(&hist[bin], 1);
    order[b * N_ + pos] = n;
  }
}

// ---------------- feat f32 -> bf16 pre-scaled by norm_s (XCD-pinned per graph) ----------------
__global__ __launch_bounds__(256) void k_f2bf_scaled(const float* __restrict__ in,
                                                     const float* __restrict__ norm_s,
                                                     unsigned short* __restrict__ out) {
  int blk = blockIdx.x;
  int b = ((blk >> 10) << 3) | (blk & 7);
  int nb = (blk >> 3) & 127;
  int t = threadIdx.x;
  int node = b * N_ + nb * 16 + (t >> 4);
  int f0 = (t & 15) * 8;
  float ns = norm_s[node];
  const float4* p = (const float4*)(in + (size_t)node * F_ + f0);
  float4 v0 = p[0], v1 = p[1];
  uint4 o;
  o.x = f2bf(v0.x * ns) | (f2bf(v0.y * ns) << 16);
  o.y = f2bf(v0.z * ns) | (f2bf(v0.w * ns) << 16);
  o.z = f2bf(v1.x * ns) | (f2bf(v1.y * ns) << 16);
  o.w = f2bf(v1.z * ns) | (f2bf(v1.w * ns) << 16);
  *(uint4*)(out + (size_t)node * F_ + f0) = o;
}

// ---------------- aggregate: 16 lanes/node, 16 nodes/block, degree-sorted node order ----------------
__global__ __launch_bounds__(256) void k_agg(const unsigned short* __restrict__ hs,
                                             const int* __restrict__ row_ptr,
                                             const int* __restrict__ csr,
                                             const float* __restrict__ norm_d,
                                             const int* __restrict__ order,
                                             unsigned short* __restrict__ agg) {
  int blk = blockIdx.x;
  int b = ((blk >> 10) << 3) | (blk & 7);
  int nb = (blk >> 3) & 127;
  int t = threadIdx.x;
  int nl = t >> 4, f8 = t & 15;
  int n = order[b * N_ + nb * 16 + nl];          // degree-sorted: block nodes have similar degree
  int node = b * N_ + n;
  int r0 = row_ptr[b * (N_ + 1) + n], r1 = row_ptr[b * (N_ + 1) + n + 1];
  const int* cs = csr + (size_t)b * E_;
  const unsigned short* hb = hs + ((size_t)b * N_) * F_ + f8 * 8;
  float a0 = 0.f, a1 = 0.f, a2 = 0.f, a3 = 0.f, a4 = 0.f, a5 = 0.f, a6 = 0.f, a7 = 0.f;
#define ACC8(u) { a0 += bf2f(u.x); a1 += bf2f(u.x >> 16); a2 += bf2f(u.y); a3 += bf2f(u.y >> 16); \
                  a4 += bf2f(u.z); a5 += bf2f(u.z >> 16); a6 += bf2f(u.w); a7 += bf2f(u.w >> 16); }
  int e = r0;
  for (; e + 8 <= r1; e += 8) {
    int s0 = cs[e],     s1 = cs[e + 1], s2 = cs[e + 2], s3 = cs[e + 3];
    int s4 = cs[e + 4], s5 = cs[e + 5], s6 = cs[e + 6], s7 = cs[e + 7];
    uint4 u0 = *(const uint4*)(hb + (size_t)s0 * F_);
    uint4 u1 = *(const uint4*)(hb + (size_t)s1 * F_);
    uint4 u2 = *(const uint4*)(hb + (size_t)s2 * F_);
    uint4 u3 = *(const uint4*)(hb + (size_t)s3 * F_);
    uint4 u4 = *(const uint4*)(hb + (size_t)s4 * F_);
    uint4 u5 = *(const uint4*)(hb + (size_t)s5 * F_);
    uint4 u6 = *(const uint4*)(hb + (size_t)s6 * F_);
    uint4 u7 = *(const uint4*)(hb + (size_t)s7 * F_);
    ACC8(u0); ACC8(u1); ACC8(u2); ACC8(u3);
    ACC8(u4); ACC8(u5); ACC8(u6); ACC8(u7);
  }
  for (; e < r1; ++e) {
    int s0 = cs[e];
    uint4 u0 = *(const uint4*)(hb + (size_t)s0 * F_);
    ACC8(u0);
  }
#undef ACC8
  float wd = norm_d[node];
  uint4 o;
  o.x = f2bf(a0 * wd) | (f2bf(a1 * wd) << 16);
  o.y = f2bf(a2 * wd) | (f2bf(a3 * wd) << 16);
  o.z = f2bf(a4 * wd) | (f2bf(a5 * wd) << 16);
  o.w = f2bf(a6 * wd) | (f2bf(a7 * wd) << 16);
  *(uint4*)(agg + (size_t)node * F_ + f8 * 8) = o;
}

// ---------------- pack W (f32 [128k][128n]) into MFMA fragment layout, bf16 hi/lo ----------------
__global__ __launch_bounds__(256) void k_packW(const float* __restrict__ W,
                                               unsigned short* __restrict__ wp_hi,
                                               unsigned short* __restrict__ wp_lo) {
  int tid = blockIdx.x * 256 + threadIdx.x;
  int lane = tid & 63, frag = tid >> 6;
  if (frag >= 32) return;
  int kt = frag >> 3, nt = frag & 7;
  int k0 = kt * 32 + (lane >> 4) * 8;
  int n = nt * 16 + (lane & 15);
  for (int j = 0; j < 8; j++) {
    float w = W[(size_t)(k0 + j) * 128 + n];
    unsigned int hi = f2bf(w);
    float whi = bf2f(hi);
    unsigned int lo = f2bf(w - whi);
    wp_hi[(size_t)tid * 8 + j] = (unsigned short)hi;
    wp_lo[(size_t)tid * 8 + j] = (unsigned short)lo;
  }
}

// ---------------- MFMA GEMM (transposed) + LDS-staged coalesced epilogue + fused score-y ----------------
// XCD-pinned: blockIdx = (b>>3)*128 + nb*8 + (b&7), nb in [0,16). 32 nodes/wave.
// ymode: 0 = y  = partial; 1 = y += partial; 2 = y = (y+partial)*norm_s (finalize)
template <bool WRITE_HS>
__global__ __launch_bounds__(256) void k_gemm_mfma(const unsigned short* __restrict__ agg,
                                                   const unsigned short* __restrict__ wp_hi,
                                                   const unsigned short* __restrict__ wp_lo,
                                                   const float* __restrict__ bias,
                                                   unsigned short* __restrict__ cr,
                                                   int out_off,
                                                   const float* __restrict__ norm_s,
                                                   unsigned short* __restrict__ hs,
                                                   const float* __restrict__ Wsc,
                                                   float* __restrict__ ybuf,
                                                   int ymode) {
  __shared__ unsigned short Stg[128 * F_];       // 32 KB staging
  int blk = blockIdx.x;
  int b = ((blk >> 7) << 3) | (blk & 7);
  int nb = (blk >> 3) & 15;
  int t = threadIdx.x;
  int wave = t >> 6, lane = t & 63;
  int gbase = b * N_ + nb * 128;
  int rl0 = wave * 32;
  int arow = lane & 15, kg = lane >> 4;

  f32x4 acc[2][8];
#pragma unroll
  for (int i = 0; i < 2; i++)
#pragma unroll
    for (int j = 0; j < 8; j++) acc[i][j] = (f32x4){0.f, 0.f, 0.f, 0.f};

#pragma unroll
  for (int kt = 0; kt < 4; ++kt) {
    bf16x8 a0 = *(const bf16x8*)(agg + (size_t)(gbase + rl0 + arow) * F_ + kt * 32 + kg * 8);
    bf16x8 a1 = *(const bf16x8*)(agg + (size_t)(gbase + rl0 + 16 + arow) * F_ + kt * 32 + kg * 8);
    const unsigned short* bh = wp_hi + ((size_t)(kt * 8) * 64 + lane) * 8;
    const unsigned short* bl = wp_lo + ((size_t)(kt * 8) * 64 + lane) * 8;
#pragma unroll
    for (int nt = 0; nt < 8; ++nt) {
      bf16x8 bhv = *(const bf16x8*)(bh + (size_t)nt * 64 * 8);
      bf16x8 blv = *(const bf16x8*)(bl + (size_t)nt * 64 * 8);
      acc[0][nt] = __builtin_amdgcn_mfma_f32_16x16x32_bf16(bhv, a0, acc[0][nt], 0, 0, 0);
      acc[0][nt] = __builtin_amdgcn_mfma_f32_16x16x32_bf16(blv, a0, acc[0][nt], 0, 0, 0);
      acc[1][nt] = __builtin_amdgcn_mfma_f32_16x16x32_bf16(bhv, a1, acc[1][nt], 0, 0, 0);
      acc[1][nt] = __builtin_amdgcn_mfma_f32_16x16x32_bf16(blv, a1, acc[1][nt], 0, 0, 0);
    }
  }

  int fb = kg * 4;
  int l0 = rl0 + arow, l1 = rl0 + 16 + arow;
  float yp0 = 0.f, yp1 = 0.f;
#pragma unroll
  for (int nt = 0; nt < 8; ++nt) {
    float4 bv = *(const float4*)(bias + nt * 16 + fb);
    acc[0][nt][0] += bv.x; acc[0][nt][1] += bv.y; acc[0][nt][2] += bv.z; acc[0][nt][3] += bv.w;
    acc[1][nt][0] += bv.x; acc[1][nt][1] += bv.y; acc[1][nt][2] += bv.z; acc[1][nt][3] += bv.w;
    uint2 p0, p1;
    p0.x = f2bf(acc[0][nt][0]) | (f2bf(acc[0][nt][1]) << 16);
    p0.y = f2bf(acc[0][nt][2]) | (f2bf(acc[0][nt][3]) << 16);
    p1.x = f2bf(acc[1][nt][0]) | (f2bf(acc[1][nt][1]) << 16);
    p1.y = f2bf(acc[1][nt][2]) | (f2bf(acc[1][nt][3]) << 16);
    *(uint2*)&Stg[swz(l0, nt * 16 + fb)] = p0;
    *(uint2*)&Stg[swz(l1, nt * 16 + fb)] = p1;
    float4 wv = *(const float4*)(Wsc + out_off + nt * 16 + fb);
    yp0 += bf2f(p0.x) * wv.x + bf2f(p0.x >> 16) * wv.y + bf2f(p0.y) * wv.z + bf2f(p0.y >> 16) * wv.w;
    yp1 += bf2f(p1.x) * wv.x + bf2f(p1.x >> 16) * wv.y + bf2f(p1.y) * wv.z + bf2f(p1.y >> 16) * wv.w;
  }
  yp0 += __shfl_xor(yp0, 16); yp0 += __shfl_xor(yp0, 32);
  yp1 += __shfl_xor(yp1, 16); yp1 += __shfl_xor(yp1, 32);
  if (kg == 0) {
    int n0 = gbase + l0, n1 = gbase + l1;
    if (ymode == 0)      { ybuf[n0] = yp0; ybuf[n1] = yp1; }
    else if (ymode == 1) { ybuf[n0] += yp0; ybuf[n1] += yp1; }
    else                 { ybuf[n0] = (ybuf[n0] + yp0) * norm_s[n0];
                           ybuf[n1] = (ybuf[n1] + yp1) * norm_s[n1]; }
  }

  int rrow = lane >> 4, chunk = lane & 15;
#pragma unroll
  for (int it = 0; it < 8; ++it) {
    int rl = rl0 + it * 4 + rrow;
    uint4 vv = *(const uint4*)&Stg[swz(rl, chunk * 8)];
    *(uint4*)(cr + (size_t)(gbase + rl) * C_ + out_off + chunk * 8) = vv;
  }
  if (WRITE_HS) {
    float ns0 = norm_s[gbase + l0];
    float ns1 = norm_s[gbase + l1];
#pragma unroll
    for (int nt = 0; nt < 8; ++nt) {
      uint2 q0, q1;
      q0.x = f2bf(acc[0][nt][0] * ns0) | (f2bf(acc[0][nt][1] * ns0) << 16);
      q0.y = f2bf(acc[0][nt][2] * ns0) | (f2bf(acc[0][nt][3] * ns0) << 16);
      q1.x = f2bf(acc[1][nt][0] * ns1) | (f2bf(acc[1][nt][1] * ns1) << 16);
      q1.y = f2bf(acc[1][nt][2] * ns1) | (f2bf(acc[1][nt][3] * ns1) << 16);
      *(uint2*)&Stg[swz(l0, nt * 16 + fb)] = q0;
      *(uint2*)&Stg[swz(l1, nt * 16 + fb)] = q1;
    }
#pragma unroll
    for (int it = 0; it < 8; ++it) {
      int rl = rl0 + it * 4 + rrow;
      uint4 vv = *(const uint4*)&Stg[swz(rl, chunk * 8)];
      *(uint4*)(hs + (size_t)(gbase + rl) * F_ + chunk * 8) = vv;
    }
  }
}

// ---------------- score stage 2: score[n] = norm_d[n] * sum_in y[src] + bs ----------------
__global__ __launch_bounds__(256) void k_score_agg(const float* __restrict__ y,
                                                   const int* __restrict__ row_ptr,
                                                   const int* __restrict__ csr,
                                                   const float* __restrict__ norm_d,
                                                   const float* __restrict__ bs,
                                                   float* __restrict__ score) {
  int node = blockIdx.x * 256 + threadIdx.x;
  int b = node >> 11, n = node & (N_ - 1);
  int r0 = row_ptr[b * (N_ + 1) + n], r1 = row_ptr[b * (N_ + 1) + n + 1];
  const int* cs = csr + (size_t)b * E_;
  float a = 0.f;
  for (int e = r0; e < r1; ++e) a += y[b * N_ + cs[e]];
  score[node] = norm_d[node] * a + bs[0];
}

// ---------------- top-k selection per graph; emits compacted indices + tanh weights ----------------
__global__ __launch_bounds__(256) void k_topk(const float* __restrict__ score,
                                              int* __restrict__ idxs,
                                              float* __restrict__ wsel) {
  __shared__ unsigned int keys[N_];
  __shared__ int red[256];
  int b = blockIdx.x, t = threadIdx.x;
  for (int i = t; i < N_; i += 256) {
    unsigned u = __float_as_uint(score[b * N_ + i]);
    keys[i] = (u & 0x80000000u) ? ~u : (u | 0x80000000u);
  }
  __syncthreads();
  unsigned prefix = 0;
  for (int bit = 31; bit >= 0; bit--) {
    unsigned cand = prefix | (1u << bit);
    int c = 0;
    for (int i = t; i < N_; i += 256) c += ((keys[i] >> bit) >= (cand >> bit));
    red[t] = c;
    __syncthreads();
    for (int off = 128; off > 0; off >>= 1) { if (t < off) red[t] += red[t + off]; __syncthreads(); }
    if (red[0] >= K_) prefix = cand;
    __syncthreads();
  }
  unsigned T = prefix;
  int c = 0;
  for (int i = t; i < N_; i += 256) c += (keys[i] > T);
  red[t] = c;
  __syncthreads();
  for (int off = 128; off > 0; off >>= 1) { if (t < off) red[t] += red[t + off]; __syncthreads(); }
  int R = K_ - red[0];                          // ties to take, index order
  __syncthreads();
  unsigned kk[8]; int myt = 0;
  for (int j = 0; j < 8; j++) { kk[j] = keys[t * 8 + j]; myt += (kk[j] == T); }
  red[t] = myt;
  __syncthreads();
  for (int off = 1; off < 256; off <<= 1) {
    int x = (t >= off) ? red[t - off] : 0;
    __syncthreads();
    red[t] += x;
    __syncthreads();
  }
  int rank = red[t] - myt;
  bool sb[8]; int csel = 0;
  for (int j = 0; j < 8; j++) {
    bool tie = (kk[j] == T);
    bool sel = (kk[j] > T) || (tie && rank < R);
    if (tie) rank++;
    sb[j] = sel; csel += sel;
  }
  __syncthreads();
  red[t] = csel;
  __syncthreads();
  for (int off = 1; off < 256; off <<= 1) {
    int x = (t >= off) ? red[t - off] : 0;
    __syncthreads();
    red[t] += x;
    __syncthreads();
  }
  int pos = red[t] - csel;
  for (int j = 0; j < 8; j++) {
    if (sb[j]) {
      int i = t * 8 + j;
      idxs[b * K_ + pos] = i;
      wsel[b * K_ + pos] = tanhf(score[b * N_ + i]);
      pos++;
    }
  }
}

// ---------------- readout partials over SELECTED rows only ----------------
__global__ __launch_bounds__(384) void k_readout_part(const unsigned short* __restrict__ cr,
                                                      const float* __restrict__ wsel,
                                                      const int* __restrict__ idxs,
                                                      float* __restrict__ psum,
                                                      float* __restrict__ pmax) {
  __shared__ int rows[64];
  __shared__ float wv[64];
  int b = blockIdx.x >> 4, ch = blockIdx.x & 15;
  int f = threadIdx.x;
  if (f < 64) {
    rows[f] = idxs[b * K_ + ch * 64 + f];
    wv[f] = wsel[b * K_ + ch * 64 + f];
  }
  __syncthreads();
  float sum = 0.f, mx = -3.402823466e38f;
  for (int s = 0; s < 64; s++) {
    float v = bf2f(cr[((size_t)(b * N_ + rows[s])) * C_ + f]);
    float x = v * wv[s];
    sum += x; mx = fmaxf(mx, x);
  }
  psum[((size_t)b * 16 + ch) * C_ + f] = sum;
  pmax[((size_t)b * 16 + ch) * C_ + f] = mx;
}

__global__ __launch_bounds__(384) void k_readout_red(const float* __restrict__ psum,
                                                     const float* __restrict__ pmax,
                                                     float* __restrict__ g) {
  int b = blockIdx.x, f = threadIdx.x;
  float s = 0.f, m = -3.402823466e38f;
  for (int ch = 0; ch < 16; ch++) {
    s += psum[((size_t)b * 16 + ch) * C_ + f];
    m = fmaxf(m, pmax[((size_t)b * 16 + ch) * C_ + f]);
  }
  g[b * 768 + f] = s * (1.f / K_);
  g[b * 768 + C_ + f] = m;
}

// ---------------- MLP layer 1: h1 = g @ w1 ----------------
__global__ __launch_bounds__(128) void k_mlp1(const float* __restrict__ g,
                                              const float* __restrict__ w1,
                                              float* __restrict__ h1) {
  __shared__ float gr[768];
  int b = blockIdx.x, t = threadIdx.x;
  for (int i = t; i < 768; i += 128) gr[i] = g[b * 768 + i];
  __syncthreads();
  float acc = 0.f;
  for (int k = 0; k < 768; k++) acc += gr[k] * w1[(size_t)k * 128 + t];
  h1[b * 128 + t] = acc;
}

// ---------------- BN + ReLU + mlp_w2 + log_softmax ----------------
__global__ __launch_bounds__(128) void k_mlp2(const float* __restrict__ h1,
                                              const float* __restrict__ bn_g,
                                              const float* __restrict__ bn_b,
                                              const float* __restrict__ w2,
                                              float* __restrict__ out) {
  __shared__ float hn[64][128];
  __shared__ float o[64][10];
  int t = threadIdx.x;   // 128
  float mean = 0.f;
  for (int r = 0; r < 64; r++) mean += h1[r * 128 + t];
  mean *= (1.f / 64.f);
  float var = 0.f;
  for (int r = 0; r < 64; r++) { float d = h1[r * 128 + t] - mean; var += d * d; }
  var *= (1.f / 64.f);
  float sc = bn_g[t] * rsqrtf(var + 1e-5f), sh = bn_b[t];
  for (int r = 0; r < 64; r++) {
    float v = (h1[r * 128 + t] - mean) * sc + sh;
    hn[r][t] = fmaxf(v, 0.f);
  }
  __syncthreads();
  for (int j = 0; j < 5; j++) {
    int idx = t + j * 128;           // 0..639
    int r = idx / 10, c = idx % 10;
    float a = 0.f;
    for (int k = 0; k < 128; k++) a += hn[r][k] * w2[k * 10 + c];
    o[r][c] = a;
  }
  __syncthreads();
  if (t < 64) {
    float mx = -3.402823466e38f;
    for (int c = 0; c < 10; c++) mx = fmaxf(mx, o[t][c]);
    float se = 0.f;
    for (int c = 0; c < 10; c++) se += expf(o[t][c] - mx);
    float l = logf(se);
    for (int c = 0; c < 10; c++) out[t * 10 + c] = o[t][c] - mx - l;
  }
}

extern "C" void kernel_launch(void* const* d_in, const int* in_sizes, int n_in,
                              void* d_out, int out_size, void* d_ws, size_t ws_size,
                              hipStream_t stream) {
  const float* feat = (const float*)d_in[0];
  const int* src = (const int*)d_in[1];
  const int* dst = (const int*)d_in[2];
  const float* W0 = (const float*)d_in[3];  const float* b0 = (const float*)d_in[4];
  const float* W1 = (const float*)d_in[5];  const float* b1 = (const float*)d_in[6];
  const float* W2 = (const float*)d_in[7];  const float* b2 = (const float*)d_in[8];
  const float* Ws = (const float*)d_in[9];  const float* bs = (const float*)d_in[10];
  const float* mw1 = (const float*)d_in[11];
  const float* bng = (const float*)d_in[12];
  const float* bnb = (const float*)d_in[13];
  const float* mw2 = (const float*)d_in[14];
  float* out = (float*)d_out;

  char* p = (char*)d_ws;
  auto alloc = [&](size_t bytes) -> void* {
    void* r = (void*)p;
    p += (bytes + 255) & ~(size_t)255;
    return r;
  };
  int* row_ptr = (int*)alloc((size_t)B_ * (N_ + 1) * 4);
  float* norm_s = (float*)alloc((size_t)NB_ * 4);
  float* norm_d = (float*)alloc((size_t)NB_ * 4);
  int* csr      = (int*)alloc((size_t)B_ * E_ * 4);
  int* order    = (int*)alloc((size_t)NB_ * 4);
  unsigned short* cr  = (unsigned short*)alloc((size_t)NB_ * C_ * 2);
  unsigned short* agg = (unsigned short*)alloc((size_t)NB_ * F_ * 2);   // A buffer
  unsigned short* hsb = (unsigned short*)alloc((size_t)NB_ * F_ * 2);   // H buffer
  float* y     = (float*)alloc((size_t)NB_ * 4);
  float* score = (float*)alloc((size_t)NB_ * 4);
  int* idxs    = (int*)alloc((size_t)B_ * K_ * 4);
  float* wsel  = (float*)alloc((size_t)B_ * K_ * 4);
  float* psum  = (float*)alloc((size_t)B_ * 16 * C_ * 4);
  float* pmax  = (float*)alloc((size_t)B_ * 16 * C_ * 4);
  float* g     = (float*)alloc((size_t)B_ * 768 * 4);
  float* h1    = (float*)alloc((size_t)B_ * 128 * 4);
  unsigned short* wp0h = (unsigned short*)alloc(16384 * 2);
  unsigned short* wp0l = (unsigned short*)alloc(16384 * 2);
  unsigned short* wp1h = (unsigned short*)alloc(16384 * 2);
  unsigned short* wp1l = (unsigned short*)alloc(16384 * 2);
  unsigned short* wp2h = (unsigned short*)alloc(16384 * 2);
  unsigned short* wp2l = (unsigned short*)alloc(16384 * 2);

  // prep: 4 blocks per graph, range-partitioned, no global atomics
  k_prep<<<dim3(B_ * 4), dim3(1024), 0, stream>>>(src, dst, norm_s, norm_d, row_ptr, csr);
  // per-graph degree sort (descending) -> processing order for k_agg
  k_sort<<<dim3(B_), dim3(256), 0, stream>>>(row_ptr, order);

  // weight packs
  k_packW<<<dim3(8), dim3(256), 0, stream>>>(W0, wp0h, wp0l);
  k_packW<<<dim3(8), dim3(256), 0, stream>>>(W1, wp1h, wp1l);
  k_packW<<<dim3(8), dim3(256), 0, stream>>>(W2, wp2h, wp2l);

  // hs0 = feat * norm_s (bf16), XCD-pinned
  k_f2bf_scaled<<<dim3(NB_ / 16), dim3(256), 0, stream>>>(feat, norm_s, hsb);

  // layer 0
  k_agg<<<dim3(NB_ / 16), dim3(256), 0, stream>>>(hsb, row_ptr, csr, norm_d, order, agg);
  k_gemm_mfma<true><<<dim3(NB_ / 128), dim3(256), 0, stream>>>(agg, wp0h, wp0l, b0, cr, 0,
                                                               norm_s, hsb, Ws, y, 0);
  // layer 1
  k_agg<<<dim3(NB_ / 16), dim3(256), 0, stream>>>(hsb, row_ptr, csr, norm_d, order, agg);
  k_gemm_mfma<true><<<dim3(NB_ / 128), dim3(256), 0, stream>>>(agg, wp1h, wp1l, b1, cr, 128,
                                                               norm_s, hsb, Ws, y, 1);
  // layer 2 (finalize y)
  k_agg<<<dim3(NB_ / 16), dim3(256), 0, stream>>>(hsb, row_ptr, csr, norm_d, order, agg);
  k_gemm_mfma<false><<<dim3(NB_ / 128), dim3(256), 0, stream>>>(agg, wp2h, wp2l, b2, cr, 256,
                                                                norm_s, nullptr, Ws, y, 2);

  // SAGPool score aggregation + top-k (compacted)
  k_score_agg<<<dim3(NB_ / 256), dim3(256), 0, stream>>>(y, row_ptr, csr, norm_d, bs, score);
  k_topk<<<dim3(B_), dim3(256), 0, stream>>>(score, idxs, wsel);

  // readout over selected rows
  k_readout_part<<<dim3(B_ * 16), dim3(384), 0, stream>>>(cr, wsel, idxs, psum, pmax);
  k_readout_red<<<dim3(B_), dim3(384), 0, stream>>>(psum, pmax, g);

  // MLP
  k_mlp1<<<dim3(B_), dim3(128), 0, stream>>>(g, mw1, h1);
  k_mlp2<<<dim3(1), dim3(128), 0, stream>>>(h1, bng, bnb, mw2, out);
}